// Round 6
// baseline (227.640 us; speedup 1.0000x reference)
//
#include <hip/hip_runtime.h>
#include <math.h>

#define NP   132
#define NV   67            // Hermitian half-spectrum (0..66), 66 = Nyquist
#define NPP  (NP*NP)       // 17424
#define NCH  64
#define NIMG 256
#define NX   128
#define NO   256
#define TWO_PI 6.2831853071795864769f

// ws layout (floats):
//   H   : [NCH ][NV][132][2]   transfer fn, [c][v][u]
//   A   : [NIMG][132][68][2]   row-DFT of y, [row][v] (68 = padded 67)
//   U   : [NIMG][NV][132][2]   col-roundtrip result, [v][n0]
//   rho : [NIMG][NPP]          real correction image
static const size_t OFF_H   = 0;
static const size_t OFF_A   = OFF_H + (size_t)NCH*NV*NP*2;
static const size_t OFF_U   = OFF_A + (size_t)NIMG*NP*68*2;
static const size_t OFF_RHO = OFF_U + (size_t)NIMG*NV*NP*2;

// i-power sign/swap: multiplier i^p (g-form) or (-i)^p (f-form)
#define TR0(t) (t.x)
#define TI0(t) (t.y)
#define TR1(t) (-(t.y))
#define TI1(t) (t.x)
#define TR2(t) (-(t.x))
#define TI2(t) (-(t.y))
#define TR3(t) (t.y)
#define TI3(t) (-(t.x))
#define CMACF(xr, xi, dr, di, TRv, TIv) { xr += (dr)*(TRv) + (di)*(TIv); xi += (di)*(TRv) - (dr)*(TIv); }
#define CMACG(xr, xi, dr, di, TRv, TIv) { xr += (dr)*(TRv) - (di)*(TIv); xi += (di)*(TRv) + (dr)*(TIv); }

// rotate twiddle (TR_,TI_) by w3 = e^{i*3*theta}
#define ROT3(TR_, TI_) { float nt_ = TR_*w3r - TI_*w3i; TI_ = TR_*w3i + TI_*w3r; TR_ = nt_; }
// init three twiddle chains t0=1, t1=w, t2=w^2 and w3=w^3 from (c33,s33)
#define TWIDDLE3_INIT() \
    float t0r = 1.f, t0i = 0.f, t1r = c33, t1i = s33; \
    float c2_ = c33*c33 - s33*s33, s2_ = 2.f*c33*s33; \
    float t2r = c2_, t2i = s2_; \
    float w3r = c2_*c33 - s2_*s33, w3i = s2_*c33 + c2_*s33;

__global__ __launch_bounds__(256) void k_compute_H(
    const float* __restrict__ wgt, const float* __restrict__ bias,
    float2* __restrict__ H) {
  int idx = blockIdx.x * 256 + threadIdx.x;   // over NV*NP
  int c = blockIdx.y;
  if (idx >= NV*NP) return;
  int u = idx % NP, v = idx / NP;
  float k[3][3];
#pragma unroll
  for (int i = 0; i < 3; i++)
#pragma unroll
    for (int j = 0; j < 3; j++) k[i][j] = wgt[c*9 + i*3 + j];
  float invW = 0.f;
#pragma unroll
  for (int p0 = -1; p0 <= 1; p0++)
#pragma unroll
    for (int p1 = -1; p1 <= 1; p1++) {
      float s = 0.f;
#pragma unroll
      for (int i = 0; i < 3; i++)
#pragma unroll
        for (int j = 0; j < 3; j++) {
          int i2 = i - 2*p0, j2 = j - 2*p1;
          if (i2 >= 0 && i2 < 3 && j2 >= 0 && j2 < 3) s += k[i][j]*k[i2][j2];
        }
      float ang = TWO_PI * (float)(u*p0 + v*p1) / (float)NP;
      invW += s * cosf(ang);
    }
  float B00 = k[0][0]+k[0][1]+k[1][0]+k[1][1];
  float B10 = k[2][0]+k[2][1];
  float B01 = k[0][2]+k[1][2];
  float B11 = k[2][2];
  float su, cu, sv, cv, suv, cuv;
  sincosf(TWO_PI*(float)u/(float)NP, &su, &cu);
  sincosf(TWO_PI*(float)v/(float)NP, &sv, &cv);
  sincosf(TWO_PI*(float)(u+v)/(float)NP, &suv, &cuv);
  float Bre = B00 + B10*cu + B01*cv + B11*cuv;
  float Bim = -(B10*su + B01*sv + B11*suv);
  float alpha = 1.f/(1.f + expf(9.f - bias[c])) + 1e-5f;
  float d = invW + alpha;
  H[((size_t)c*NV + v)*NP + u] = make_float2((1.f - Bre)/d, (-Bim)/d);
}

#define RLST 7   // float4 stride per spectral/spatial row: 7 f4 = 14 rowpairs

// S1 row-DFT, two-for-one + radix-4 (132 = 4*33).
// Inner loop: 11 groups x 3 sub-steps (rows 12g..12g+11), three independent
// twiddle chains rotated by w^3 -> no copy-movs, batched ds_reads.
__global__ __launch_bounds__(256, 5) void k_s1(
    const float* __restrict__ x, float2* __restrict__ A) {
  __shared__ __align__(16) float4 la[(NP+4)*RLST];
  float2* la2 = (float2*)la;
  int tid = threadIdx.x, img = blockIdx.y, row0 = blockIdx.x*28;
  const float* xim = x + (size_t)img*NX*NX;
  int rmax = NP - row0;                       // 28 or 20 (last block)
  for (int e = tid; e < NP*14; e += 256) {
    int n1 = e % NP, j = e / NP;              // j = rowpair 0..13
    float2 z = make_float2(0.f, 0.f);
    if (2*j + 1 < rmax) {
      int col = (n1 + 126) & 127;
      int ra = (row0 + 2*j + 126) & 127;
      int rb = (row0 + 2*j + 127) & 127;
      z = make_float2(xim[ra*NX + col], xim[rb*NX + col]);
    }
    la2[n1*14 + j] = z;
  }
  __syncthreads();
  int rpg = tid / 33, q = tid - rpg*33;
  int nr = rmax >> 2; if (nr > 7) nr = 7;
  bool act = (tid < 231) && (rpg < nr);
  float s33, c33; sincosf(TWO_PI*(float)q/33.f, &s33, &c33);
  float Sr[4][2], Si[4][2];
#pragma unroll
  for (int r = 0; r < 4; r++) { Sr[r][0]=0.f; Sr[r][1]=0.f; Si[r][0]=0.f; Si[r][1]=0.f; }

#define STEP41(MAC, o, TR_, TI_) { \
    float4 d0 = bp[(o)*RLST]; \
    float4 d1 = bp[((o)+1)*RLST]; \
    float4 d2 = bp[((o)+2)*RLST]; \
    float4 d3 = bp[((o)+3)*RLST]; \
    MAC(Sr[0][0], Si[0][0], d0.x, d0.y, TR_, TI_); \
    MAC(Sr[0][1], Si[0][1], d0.z, d0.w, TR_, TI_); \
    MAC(Sr[1][0], Si[1][0], d1.x, d1.y, TR_, TI_); \
    MAC(Sr[1][1], Si[1][1], d1.z, d1.w, TR_, TI_); \
    MAC(Sr[2][0], Si[2][0], d2.x, d2.y, TR_, TI_); \
    MAC(Sr[2][1], Si[2][1], d2.z, d2.w, TR_, TI_); \
    MAC(Sr[3][0], Si[3][0], d3.x, d3.y, TR_, TI_); \
    MAC(Sr[3][1], Si[3][1], d3.z, d3.w, TR_, TI_); }

  if (act) {
    TWIDDLE3_INIT();
    const float4* bp = la + rpg;
#pragma unroll 1
    for (int g = 0; g < 11; ++g) {
      STEP41(CMACF, 0, t0r, t0i) ROT3(t0r, t0i)
      STEP41(CMACF, 4, t1r, t1i) ROT3(t1r, t1i)
      STEP41(CMACF, 8, t2r, t2i) ROT3(t2r, t2i)
      bp += 12*RLST;
    }
  }
  __syncthreads();   // all input reads done before overwrite
  if (act) {
    float sw, cw; sincosf(TWO_PI*(float)q/132.f, &sw, &cw);
    float2 w1 = make_float2(cw, sw);
    float2 w2 = make_float2(cw*cw - sw*sw, 2.f*cw*sw);
    float2 w3 = make_float2(w2.x*cw - w2.y*sw, w2.x*sw + w2.y*cw);
#define COMB1(sidx, P1, P2, P3) { \
    float z0r = Sr[0][0], z0i = Si[0][0], z1r = Sr[0][1], z1i = Si[0][1]; \
    CMACF(z0r, z0i, Sr[1][0], Si[1][0], TR##P1(w1), TI##P1(w1)); \
    CMACF(z1r, z1i, Sr[1][1], Si[1][1], TR##P1(w1), TI##P1(w1)); \
    CMACF(z0r, z0i, Sr[2][0], Si[2][0], TR##P2(w2), TI##P2(w2)); \
    CMACF(z1r, z1i, Sr[2][1], Si[2][1], TR##P2(w2), TI##P2(w2)); \
    CMACF(z0r, z0i, Sr[3][0], Si[3][0], TR##P3(w3), TI##P3(w3)); \
    CMACF(z1r, z1i, Sr[3][1], Si[3][1], TR##P3(w3), TI##P3(w3)); \
    la[(q + 33*sidx)*RLST + rpg] = make_float4(z0r, z0i, z1r, z1i); }
    COMB1(0,0,0,0) COMB1(1,1,2,3) COMB1(2,2,0,2) COMB1(3,3,2,1)
#undef COMB1
  }
  __syncthreads();   // Z visible
  if (act) {
    float2* Aim = A + (size_t)img*NP*68;
    int rbase = row0 + rpg*4;
    float4 Za = la[q*RLST + rpg];                      // Z[q]
    float4 Zb = la[((NP - q) % NP)*RLST + rpg];        // Z[132-q]
    float4 Zc = la[(q + 33)*RLST + rpg];               // Z[q+33]
    float4 Zd = la[(99 - q)*RLST + rpg];               // Z[99-q]
    // v = q : E = (Zv + conj(Zm))/2 ; O = (Im Zv + Im Zm, Re Zm - Re Zv)/2
    Aim[(size_t)(rbase+0)*68 + q] = make_float2(0.5f*(Za.x+Zb.x), 0.5f*(Za.y-Zb.y));
    Aim[(size_t)(rbase+1)*68 + q] = make_float2(0.5f*(Za.y+Zb.y), 0.5f*(Zb.x-Za.x));
    Aim[(size_t)(rbase+2)*68 + q] = make_float2(0.5f*(Za.z+Zb.z), 0.5f*(Za.w-Zb.w));
    Aim[(size_t)(rbase+3)*68 + q] = make_float2(0.5f*(Za.w+Zb.w), 0.5f*(Zb.z-Za.z));
    int v2 = q + 33;
    Aim[(size_t)(rbase+0)*68 + v2] = make_float2(0.5f*(Zc.x+Zd.x), 0.5f*(Zc.y-Zd.y));
    Aim[(size_t)(rbase+1)*68 + v2] = make_float2(0.5f*(Zc.y+Zd.y), 0.5f*(Zd.x-Zc.x));
    Aim[(size_t)(rbase+2)*68 + v2] = make_float2(0.5f*(Zc.z+Zd.z), 0.5f*(Zc.w-Zd.w));
    Aim[(size_t)(rbase+3)*68 + v2] = make_float2(0.5f*(Zc.w+Zd.w), 0.5f*(Zd.z-Zc.z));
    if (q == 0) {                                      // v = 66: A real = Z[66] parts
      float4 Ze = la[66*RLST + rpg];
      Aim[(size_t)(rbase+0)*68 + 66] = make_float2(Ze.x, 0.f);
      Aim[(size_t)(rbase+1)*68 + 66] = make_float2(Ze.y, 0.f);
      Aim[(size_t)(rbase+2)*68 + 66] = make_float2(Ze.z, 0.f);
      Aim[(size_t)(rbase+3)*68 + 66] = make_float2(Ze.w, 0.f);
    }
  }
}

// Fused S2+S3, radix-4 Cooley-Tukey (132 = 4*33), in-place LDS round-trip.
// ONE q per lane: (jj 0..6 [2 v each]) x (q 0..32) = 231/256 active lanes.
// Inner loops: 11 groups x 3 sub-steps, three independent twiddle chains.
#define LSTRIDE 14
__global__ __launch_bounds__(256, 5) void k_s23(
    const float2* __restrict__ A, const float2* __restrict__ H,
    float2* __restrict__ U) {
  __shared__ __align__(16) float2 la[(NP+4)*LSTRIDE];  // [n0|u][14 v] + pad
  int tid = threadIdx.x, img = blockIdx.y, v0 = blockIdx.x*14;
  int c = img & 63;
  for (int e = tid; e < NP*7; e += 256) {              // float4 fill: 2 v per lane
    int j2 = e % 7, n0 = e / 7;
    int v = v0 + 2*j2;
    float4 av = make_float4(0.f, 0.f, 0.f, 0.f);
    const float2* Arow = A + ((size_t)img*NP + n0)*68;
    if (v + 1 < NV) av = *(const float4*)(Arow + v);
    else if (v < NV) { float2 t = Arow[v]; av.x = t.x; av.y = t.y; }
    *(float4*)(la + n0*LSTRIDE + 2*j2) = av;
  }
  __syncthreads();
  bool act = (tid < 231);                    // 7 jj * 33 q
  int jj = 0, q = 0;
  if (act) { jj = tid/33; q = tid - jj*33; }
  float s33, c33; sincosf(TWO_PI*(float)q/33.f, &s33, &c33);
  float sw, cw; sincosf(TWO_PI*(float)q/132.f, &sw, &cw);
  float2 w1v = make_float2(cw, sw);
  float2 w2v = make_float2(cw*cw - sw*sw, 2.f*cw*sw);
  float2 w3v = make_float2(w2v.x*cw - w2v.y*sw, w2v.x*sw + w2v.y*cw);
  float Sr[4][2], Si[4][2];                  // [r][w]
  const float2* lap = la + jj*2;
  const float2* Hc = H + (size_t)c*NV*NP;

#define STEP42(MAC, o, TR_, TI_) { \
    float4 d0 = *(const float4*)(bp + (o)*LSTRIDE); \
    float4 d1 = *(const float4*)(bp + ((o)+1)*LSTRIDE); \
    float4 d2 = *(const float4*)(bp + ((o)+2)*LSTRIDE); \
    float4 d3 = *(const float4*)(bp + ((o)+3)*LSTRIDE); \
    MAC(Sr[0][0], Si[0][0], d0.x, d0.y, TR_, TI_); \
    MAC(Sr[0][1], Si[0][1], d0.z, d0.w, TR_, TI_); \
    MAC(Sr[1][0], Si[1][0], d1.x, d1.y, TR_, TI_); \
    MAC(Sr[1][1], Si[1][1], d1.z, d1.w, TR_, TI_); \
    MAC(Sr[2][0], Si[2][0], d2.x, d2.y, TR_, TI_); \
    MAC(Sr[2][1], Si[2][1], d2.z, d2.w, TR_, TI_); \
    MAC(Sr[3][0], Si[3][0], d3.x, d3.y, TR_, TI_); \
    MAC(Sr[3][1], Si[3][1], d3.z, d3.w, TR_, TI_); }

#define ZERO_S() { \
    _Pragma("unroll") for (int r = 0; r < 4; ++r) \
    _Pragma("unroll") for (int w = 0; w < 2; ++w) { Sr[r][w] = 0.f; Si[r][w] = 0.f; } }

#define RADIX4_LOOP(MAC) { \
    TWIDDLE3_INIT(); \
    const float2* bp = lap; \
    _Pragma("unroll 1") \
    for (int g = 0; g < 11; ++g) { \
      STEP42(MAC, 0, t0r, t0i) ROT3(t0r, t0i) \
      STEP42(MAC, 4, t1r, t1i) ROT3(t1r, t1i) \
      STEP42(MAC, 8, t2r, t2i) ROT3(t2r, t2i) \
      bp += 12*LSTRIDE; \
    } }

  // ---- phase A: forward col-DFT (f-form: multiplier conj(t)) ----
  ZERO_S();
  if (act) RADIX4_LOOP(CMACF);
  __syncthreads();   // all reads of la complete
  // ---- combine + H-mult, write T[u][j] into la ----
  if (act) {
#define COMBA(s, P1, P2, P3) { \
      int u = q + 33*(s); \
      _Pragma("unroll") \
      for (int w = 0; w < 2; ++w) { \
        float xr = Sr[0][w], xi = Si[0][w]; \
        CMACF(xr, xi, Sr[1][w], Si[1][w], TR##P1(w1v), TI##P1(w1v)); \
        CMACF(xr, xi, Sr[2][w], Si[2][w], TR##P2(w2v), TI##P2(w2v)); \
        CMACF(xr, xi, Sr[3][w], Si[3][w], TR##P3(w3v), TI##P3(w3v)); \
        int v = v0 + jj*2 + w; \
        float2 o = make_float2(0.f, 0.f); \
        if (v < NV) { float2 h = Hc[(size_t)v*NP + u]; \
          o = make_float2(xr*h.x - xi*h.y, xr*h.y + xi*h.x); } \
        la[u*LSTRIDE + jj*2 + w] = o; \
      } }
    COMBA(0,0,0,0) COMBA(1,1,2,3) COMBA(2,2,0,2) COMBA(3,3,2,1)
#undef COMBA
  }
  __syncthreads();   // T visible
  // ---- phase B: inverse col-DFT (g-form: multiplier t) ----
  ZERO_S();
  if (act) {
    RADIX4_LOOP(CMACG);
#define COMBB(s, P1, P2, P3) { \
      int n0 = q + 33*(s); \
      _Pragma("unroll") \
      for (int w = 0; w < 2; ++w) { \
        float xr = Sr[0][w], xi = Si[0][w]; \
        CMACG(xr, xi, Sr[1][w], Si[1][w], TR##P1(w1v), TI##P1(w1v)); \
        CMACG(xr, xi, Sr[2][w], Si[2][w], TR##P2(w2v), TI##P2(w2v)); \
        CMACG(xr, xi, Sr[3][w], Si[3][w], TR##P3(w3v), TI##P3(w3v)); \
        int v = v0 + jj*2 + w; \
        if (v < NV) U[((size_t)img*NV + v)*NP + n0] = make_float2(xr, xi); \
      } }
    COMBB(0,0,0,0) COMBB(1,1,2,3) COMBB(2,2,0,2) COMBB(3,3,2,1)
#undef COMBB
  }
#undef RADIX4_LOOP
#undef ZERO_S
#undef STEP42
}
#undef LSTRIDE

// S4: two-for-one inverse + radix-4. Row pairs of rho via Hermitian-extended
// spectrum W[v] = Ua_f[v] + i*Ub_f[v] (v 0..131); complex radix-4 IDFT;
// Re -> rho[row], Im -> rho[row+1]. Fill loop j-fast for coalescing;
// (row,row+1) pair fused into one aligned float4 load.
__global__ __launch_bounds__(256, 5) void k_s4(
    const float2* __restrict__ U, float* __restrict__ rho) {
  __shared__ __align__(16) float4 lu[(NP+4)*RLST];
  float2* lu2 = (float2*)lu;
  int tid = threadIdx.x, img = blockIdx.y, row0 = blockIdx.x*28;
  int rmax = NP - row0;
  const float2* Uim = U + (size_t)img*NV*NP;
  for (int e = tid; e < NP*14; e += 256) {
    int j = e % 14, v = e / 14;               // j fast: coalesced float4 runs
    float2 wv = make_float2(0.f, 0.f);
    if (2*j + 1 < rmax) {
      int row = row0 + 2*j;
      if (v < NV) {
        float4 uab = *(const float4*)(Uim + (size_t)v*NP + row);   // (ua, ub)
        wv = make_float2(uab.x - uab.w, uab.y + uab.z);
      } else {
        int vv = NP - v;   // 1..65
        float4 uab = *(const float4*)(Uim + (size_t)vv*NP + row);
        wv = make_float2(uab.x + uab.w, uab.z - uab.y);
      }
    }
    lu2[v*14 + j] = wv;
  }
  __syncthreads();
  int rpg = tid / 33, q = tid - rpg*33;
  int nr = rmax >> 2; if (nr > 7) nr = 7;
  bool act = (tid < 231) && (rpg < nr);
  float s33, c33; sincosf(TWO_PI*(float)q/33.f, &s33, &c33);
  float Sr[4][2], Si[4][2];
#pragma unroll
  for (int r = 0; r < 4; r++) { Sr[r][0]=0.f; Sr[r][1]=0.f; Si[r][0]=0.f; Si[r][1]=0.f; }
  if (act) {
    TWIDDLE3_INIT();
    const float4* bp = lu + rpg;
#pragma unroll 1
    for (int g = 0; g < 11; ++g) {
      STEP41(CMACG, 0, t0r, t0i) ROT3(t0r, t0i)
      STEP41(CMACG, 4, t1r, t1i) ROT3(t1r, t1i)
      STEP41(CMACG, 8, t2r, t2i) ROT3(t2r, t2i)
      bp += 12*RLST;
    }
  }
  if (act) {
    float sw, cw; sincosf(TWO_PI*(float)q/132.f, &sw, &cw);
    float2 w1 = make_float2(cw, sw);
    float2 w2 = make_float2(cw*cw - sw*sw, 2.f*cw*sw);
    float2 w3 = make_float2(w2.x*cw - w2.y*sw, w2.x*sw + w2.y*cw);
    float* rim = rho + (size_t)img*NPP;
    int rbase = row0 + rpg*4;
    const float scale = 1.0f/(float)NPP;
#define COMB4(sidx, P1, P2, P3) { \
    float z0r = Sr[0][0], z0i = Si[0][0], z1r = Sr[0][1], z1i = Si[0][1]; \
    CMACG(z0r, z0i, Sr[1][0], Si[1][0], TR##P1(w1), TI##P1(w1)); \
    CMACG(z1r, z1i, Sr[1][1], Si[1][1], TR##P1(w1), TI##P1(w1)); \
    CMACG(z0r, z0i, Sr[2][0], Si[2][0], TR##P2(w2), TI##P2(w2)); \
    CMACG(z1r, z1i, Sr[2][1], Si[2][1], TR##P2(w2), TI##P2(w2)); \
    CMACG(z0r, z0i, Sr[3][0], Si[3][0], TR##P3(w3), TI##P3(w3)); \
    CMACG(z1r, z1i, Sr[3][1], Si[3][1], TR##P3(w3), TI##P3(w3)); \
    int n1 = q + 33*(sidx); \
    rim[(size_t)(rbase+0)*NP + n1] = z0r*scale; \
    rim[(size_t)(rbase+1)*NP + n1] = z0i*scale; \
    rim[(size_t)(rbase+2)*NP + n1] = z1r*scale; \
    rim[(size_t)(rbase+3)*NP + n1] = z1i*scale; }
    COMB4(0,0,0,0) COMB4(1,1,2,3) COMB4(2,2,0,2) COMB4(3,3,2,1)
#undef COMB4
  }
}
#undef STEP41
#undef RLST

// epilogue: out = gelu( x_up + subpixel 3x3 taps of K over zero-upsampled rho )
__global__ __launch_bounds__(256) void k_epilogue(
    const float* __restrict__ x, const float* __restrict__ wgt,
    const float* __restrict__ rho, float* __restrict__ out) {
  int idx = blockIdx.x * 256 + threadIdx.x;
  int o1 = idx & 255;
  int o0 = (idx >> 8) & 255;
  int img = idx >> 16;
  int c = img & 63;
  int n0 = (o0 + 4) >> 1, n1 = (o1 + 4) >> 1;
  int p0 = o0 & 1, p1 = o1 & 1;
  const float* rim = rho + (size_t)img*NPP;
  int base = n0*NP + n1;
  float r00 = rim[base], r01 = rim[base+1], r10 = rim[base+NP], r11 = rim[base+NP+1];
  const float* w = wgt + c*9;
  float wa = p0 ? (p1 ? w[0] : w[1]) : (p1 ? w[3] : w[4]);
  float wb = p1 ? (p0 ? w[2] : w[5]) : 0.f;
  float wc = p0 ? (p1 ? w[6] : w[7]) : 0.f;
  float wd = (p0 & p1) ? w[8] : 0.f;
  float S = wa*r00 + wb*r01 + wc*r10 + wd*r11;
  float xv = x[(size_t)img*NX*NX + (n0-2)*NX + (n1-2)];
  float z = xv + S;
  out[idx] = 0.5f*z*(1.0f + erff(z*0.70710678118654752f));
}

extern "C" void kernel_launch(void* const* d_in, const int* in_sizes, int n_in,
                              void* d_out, int out_size, void* d_ws, size_t ws_size,
                              hipStream_t stream) {
  const float* x    = (const float*)d_in[0];
  const float* wgt  = (const float*)d_in[1];
  const float* bias = (const float*)d_in[2];
  float* ws = (float*)d_ws;
  float2* H   = (float2*)(ws + OFF_H);
  float2* A   = (float2*)(ws + OFF_A);
  float2* U   = (float2*)(ws + OFF_U);
  float*  rho = ws + OFF_RHO;
  float* out = (float*)d_out;

  k_compute_H<<<dim3((NV*NP + 255)/256, NCH), 256, 0, stream>>>(wgt, bias, H);
  k_s1 <<<dim3(5, NIMG), 256, 0, stream>>>(x, A);      // 5*28 >= 132 rows (2-for-1 radix-4)
  k_s23<<<dim3(5, NIMG), 256, 0, stream>>>(A, H, U);   // 1 q/lane, 231/256 active
  k_s4 <<<dim3(5, NIMG), 256, 0, stream>>>(U, rho);    // 5*28 >= 132 rows (2-for-1 radix-4)
  k_epilogue<<<(NIMG*NO*NO)/256, 256, 0, stream>>>(x, wgt, rho, out);
}

// Round 7
// 226.480 us; speedup vs baseline: 1.0051x; 1.0051x over previous
//
#include <hip/hip_runtime.h>
#include <math.h>

#define NP   132
#define NV   67            // Hermitian half-spectrum (0..66), 66 = Nyquist
#define NPP  (NP*NP)       // 17424
#define NCH  64
#define NIMG 256
#define NX   128
#define NO   256
#define TWO_PI 6.2831853071795864769f

// ws layout (floats):
//   H   : [NCH ][NV][132][2]   transfer fn, [c][v][u]
//   A   : [NIMG][132][68][2]   row-DFT of y, [row][v] (68 = padded 67)
//   U   : [NIMG][NV][132][2]   col-roundtrip result, [v][n0]
//   rho : [NIMG][NPP]          real correction image
static const size_t OFF_H   = 0;
static const size_t OFF_A   = OFF_H + (size_t)NCH*NV*NP*2;
static const size_t OFF_U   = OFF_A + (size_t)NIMG*NP*68*2;
static const size_t OFF_RHO = OFF_U + (size_t)NIMG*NV*NP*2;

// i-power sign/swap: multiplier i^p (g-form) or (-i)^p (f-form)
#define TR0(t) (t.x)
#define TI0(t) (t.y)
#define TR1(t) (-(t.y))
#define TI1(t) (t.x)
#define TR2(t) (-(t.x))
#define TI2(t) (-(t.y))
#define TR3(t) (t.y)
#define TI3(t) (-(t.x))
#define CMACF(xr, xi, dr, di, TRv, TIv) { xr += (dr)*(TRv) + (di)*(TIv); xi += (di)*(TRv) - (dr)*(TIv); }
#define CMACG(xr, xi, dr, di, TRv, TIv) { xr += (dr)*(TRv) - (di)*(TIv); xi += (di)*(TRv) + (dr)*(TIv); }

// rotate twiddle (TR_,TI_) by w3 = e^{i*3*theta}
#define ROT3(TR_, TI_) { float nt_ = TR_*w3r - TI_*w3i; TI_ = TR_*w3i + TI_*w3r; TR_ = nt_; }
// init three twiddle chains t0=1, t1=w, t2=w^2 and w3=w^3 from (c33,s33)
#define TWIDDLE3_INIT() \
    float t0r = 1.f, t0i = 0.f, t1r = c33, t1i = s33; \
    float c2_ = c33*c33 - s33*s33, s2_ = 2.f*c33*s33; \
    float t2r = c2_, t2i = s2_; \
    float w3r = c2_*c33 - s2_*s33, w3i = s2_*c33 + c2_*s33;

__global__ __launch_bounds__(256) void k_compute_H(
    const float* __restrict__ wgt, const float* __restrict__ bias,
    float2* __restrict__ H) {
  int idx = blockIdx.x * 256 + threadIdx.x;   // over NV*NP
  int c = blockIdx.y;
  if (idx >= NV*NP) return;
  int u = idx % NP, v = idx / NP;
  float k[3][3];
#pragma unroll
  for (int i = 0; i < 3; i++)
#pragma unroll
    for (int j = 0; j < 3; j++) k[i][j] = wgt[c*9 + i*3 + j];
  float invW = 0.f;
#pragma unroll
  for (int p0 = -1; p0 <= 1; p0++)
#pragma unroll
    for (int p1 = -1; p1 <= 1; p1++) {
      float s = 0.f;
#pragma unroll
      for (int i = 0; i < 3; i++)
#pragma unroll
        for (int j = 0; j < 3; j++) {
          int i2 = i - 2*p0, j2 = j - 2*p1;
          if (i2 >= 0 && i2 < 3 && j2 >= 0 && j2 < 3) s += k[i][j]*k[i2][j2];
        }
      float ang = TWO_PI * (float)(u*p0 + v*p1) / (float)NP;
      invW += s * cosf(ang);
    }
  float B00 = k[0][0]+k[0][1]+k[1][0]+k[1][1];
  float B10 = k[2][0]+k[2][1];
  float B01 = k[0][2]+k[1][2];
  float B11 = k[2][2];
  float su, cu, sv, cv, suv, cuv;
  sincosf(TWO_PI*(float)u/(float)NP, &su, &cu);
  sincosf(TWO_PI*(float)v/(float)NP, &sv, &cv);
  sincosf(TWO_PI*(float)(u+v)/(float)NP, &suv, &cuv);
  float Bre = B00 + B10*cu + B01*cv + B11*cuv;
  float Bim = -(B10*su + B01*sv + B11*suv);
  float alpha = 1.f/(1.f + expf(9.f - bias[c])) + 1e-5f;
  float d = invW + alpha;
  H[((size_t)c*NV + v)*NP + u] = make_float2((1.f - Bre)/d, (-Bim)/d);
}

#define RLST 7   // float4 stride per spectral/spatial row: 7 f4 = 14 rowpairs

// S1 row-DFT, two-for-one + radix-4 (132 = 4*33).
// Inner loop: 11 groups x 3 sub-steps (rows 12g..12g+11), three independent
// twiddle chains rotated by w^3 -> no copy-movs, batched ds_reads.
__global__ __launch_bounds__(256, 5) void k_s1(
    const float* __restrict__ x, float2* __restrict__ A) {
  __shared__ __align__(16) float4 la[(NP+4)*RLST];
  float2* la2 = (float2*)la;
  int tid = threadIdx.x, img = blockIdx.y, row0 = blockIdx.x*28;
  const float* xim = x + (size_t)img*NX*NX;
  int rmax = NP - row0;                       // 28 or 20 (last block)
  for (int e = tid; e < NP*14; e += 256) {
    int n1 = e % NP, j = e / NP;              // j = rowpair 0..13
    float2 z = make_float2(0.f, 0.f);
    if (2*j + 1 < rmax) {
      int col = (n1 + 126) & 127;
      int ra = (row0 + 2*j + 126) & 127;
      int rb = (row0 + 2*j + 127) & 127;
      z = make_float2(xim[ra*NX + col], xim[rb*NX + col]);
    }
    la2[n1*14 + j] = z;
  }
  __syncthreads();
  int rpg = tid / 33, q = tid - rpg*33;
  int nr = rmax >> 2; if (nr > 7) nr = 7;
  bool act = (tid < 231) && (rpg < nr);
  float s33, c33; sincosf(TWO_PI*(float)q/33.f, &s33, &c33);
  float Sr[4][2], Si[4][2];
#pragma unroll
  for (int r = 0; r < 4; r++) { Sr[r][0]=0.f; Sr[r][1]=0.f; Si[r][0]=0.f; Si[r][1]=0.f; }

#define STEP41(MAC, o, TR_, TI_) { \
    float4 d0 = bp[(o)*RLST]; \
    float4 d1 = bp[((o)+1)*RLST]; \
    float4 d2 = bp[((o)+2)*RLST]; \
    float4 d3 = bp[((o)+3)*RLST]; \
    MAC(Sr[0][0], Si[0][0], d0.x, d0.y, TR_, TI_); \
    MAC(Sr[0][1], Si[0][1], d0.z, d0.w, TR_, TI_); \
    MAC(Sr[1][0], Si[1][0], d1.x, d1.y, TR_, TI_); \
    MAC(Sr[1][1], Si[1][1], d1.z, d1.w, TR_, TI_); \
    MAC(Sr[2][0], Si[2][0], d2.x, d2.y, TR_, TI_); \
    MAC(Sr[2][1], Si[2][1], d2.z, d2.w, TR_, TI_); \
    MAC(Sr[3][0], Si[3][0], d3.x, d3.y, TR_, TI_); \
    MAC(Sr[3][1], Si[3][1], d3.z, d3.w, TR_, TI_); }

  if (act) {
    TWIDDLE3_INIT();
    const float4* bp = la + rpg;
#pragma unroll 1
    for (int g = 0; g < 11; ++g) {
      STEP41(CMACF, 0, t0r, t0i) ROT3(t0r, t0i)
      STEP41(CMACF, 4, t1r, t1i) ROT3(t1r, t1i)
      STEP41(CMACF, 8, t2r, t2i) ROT3(t2r, t2i)
      bp += 12*RLST;
    }
  }
  __syncthreads();   // all input reads done before overwrite
  if (act) {
    float sw, cw; sincosf(TWO_PI*(float)q/132.f, &sw, &cw);
    float2 w1 = make_float2(cw, sw);
    float2 w2 = make_float2(cw*cw - sw*sw, 2.f*cw*sw);
    float2 w3 = make_float2(w2.x*cw - w2.y*sw, w2.x*sw + w2.y*cw);
#define COMB1(sidx, P1, P2, P3) { \
    float z0r = Sr[0][0], z0i = Si[0][0], z1r = Sr[0][1], z1i = Si[0][1]; \
    CMACF(z0r, z0i, Sr[1][0], Si[1][0], TR##P1(w1), TI##P1(w1)); \
    CMACF(z1r, z1i, Sr[1][1], Si[1][1], TR##P1(w1), TI##P1(w1)); \
    CMACF(z0r, z0i, Sr[2][0], Si[2][0], TR##P2(w2), TI##P2(w2)); \
    CMACF(z1r, z1i, Sr[2][1], Si[2][1], TR##P2(w2), TI##P2(w2)); \
    CMACF(z0r, z0i, Sr[3][0], Si[3][0], TR##P3(w3), TI##P3(w3)); \
    CMACF(z1r, z1i, Sr[3][1], Si[3][1], TR##P3(w3), TI##P3(w3)); \
    la[(q + 33*sidx)*RLST + rpg] = make_float4(z0r, z0i, z1r, z1i); }
    COMB1(0,0,0,0) COMB1(1,1,2,3) COMB1(2,2,0,2) COMB1(3,3,2,1)
#undef COMB1
  }
  __syncthreads();   // Z visible
  if (act) {
    float2* Aim = A + (size_t)img*NP*68;
    int rbase = row0 + rpg*4;
    float4 Za = la[q*RLST + rpg];                      // Z[q]
    float4 Zb = la[((NP - q) % NP)*RLST + rpg];        // Z[132-q]
    float4 Zc = la[(q + 33)*RLST + rpg];               // Z[q+33]
    float4 Zd = la[(99 - q)*RLST + rpg];               // Z[99-q]
    // v = q : E = (Zv + conj(Zm))/2 ; O = (Im Zv + Im Zm, Re Zm - Re Zv)/2
    Aim[(size_t)(rbase+0)*68 + q] = make_float2(0.5f*(Za.x+Zb.x), 0.5f*(Za.y-Zb.y));
    Aim[(size_t)(rbase+1)*68 + q] = make_float2(0.5f*(Za.y+Zb.y), 0.5f*(Zb.x-Za.x));
    Aim[(size_t)(rbase+2)*68 + q] = make_float2(0.5f*(Za.z+Zb.z), 0.5f*(Za.w-Zb.w));
    Aim[(size_t)(rbase+3)*68 + q] = make_float2(0.5f*(Za.w+Zb.w), 0.5f*(Zb.z-Za.z));
    int v2 = q + 33;
    Aim[(size_t)(rbase+0)*68 + v2] = make_float2(0.5f*(Zc.x+Zd.x), 0.5f*(Zc.y-Zd.y));
    Aim[(size_t)(rbase+1)*68 + v2] = make_float2(0.5f*(Zc.y+Zd.y), 0.5f*(Zd.x-Zc.x));
    Aim[(size_t)(rbase+2)*68 + v2] = make_float2(0.5f*(Zc.z+Zd.z), 0.5f*(Zc.w-Zd.w));
    Aim[(size_t)(rbase+3)*68 + v2] = make_float2(0.5f*(Zc.w+Zd.w), 0.5f*(Zd.z-Zc.z));
    if (q == 0) {                                      // v = 66: A real = Z[66] parts
      float4 Ze = la[66*RLST + rpg];
      Aim[(size_t)(rbase+0)*68 + 66] = make_float2(Ze.x, 0.f);
      Aim[(size_t)(rbase+1)*68 + 66] = make_float2(Ze.y, 0.f);
      Aim[(size_t)(rbase+2)*68 + 66] = make_float2(Ze.z, 0.f);
      Aim[(size_t)(rbase+3)*68 + 66] = make_float2(Ze.w, 0.f);
    }
  }
}

// Fused S2+S3, radix-4 CT (132 = 4*33), LDS round-trip, LDS-traffic-min form:
// layout la[m][j][r] (n0 = 4m+r) puts the 4 radix rows of one column in
// contiguous 32 B -> one m-step = 2 ds_read_b128 (was 4).
// Lane map: jj 0..13 (ONE v-column) x qq 0..16 (carries q=qq and q=qq+17;
// qq=16's partner q=33 is a phantom, skipped at combine) = 238/256 lanes.
// Reads per lane per phase: 66 b128 (was 132) at same FMA count.
#define MST 56   // float2 per m-row: 14 cols x 4 r-slots
__global__ __launch_bounds__(256, 5) void k_s23(
    const float2* __restrict__ A, const float2* __restrict__ H,
    float2* __restrict__ U) {
  __shared__ __align__(16) float2 la[33*MST];   // [m][j][r]
  int tid = threadIdx.x, img = blockIdx.y, v0 = blockIdx.x*14;
  int c = img & 63;
  for (int e = tid; e < NP*7; e += 256) {       // float4 fill: 2 v per item
    int j2 = e % 7, n0 = e / 7;
    int vv = v0 + 2*j2;
    float4 av = make_float4(0.f, 0.f, 0.f, 0.f);
    const float2* Arow = A + ((size_t)img*NP + n0)*68;
    if (vv + 1 < NV) av = *(const float4*)(Arow + vv);
    else if (vv < NV) { float2 t = Arow[vv]; av.x = t.x; av.y = t.y; }
    int base = (n0 >> 2)*MST + (n0 & 3);
    la[base + (2*j2)*4]   = make_float2(av.x, av.y);
    la[base + (2*j2+1)*4] = make_float2(av.z, av.w);
  }
  __syncthreads();
  bool act = (tid < 238);                    // 14 jj * 17 qq
  int jj = 0, qq = 0;
  if (act) { jj = tid/17; qq = tid - jj*17; }
  int q2 = qq + 17;
  bool ph2 = (q2 >= 33);                     // phantom partner (qq==16)
  int v = v0 + jj;
  float sa, ca, sb, cb;
  sincosf(TWO_PI*(float)qq/33.f, &sa, &ca);
  sincosf(TWO_PI*(float)q2/33.f, &sb, &cb);
  float Sr[4][2], Si[4][2];                  // [r][qsel]
  const float2* Hc = H + (size_t)c*NV*NP;
  const float2* lap = la + jj*4;

#define ZERO_S() { \
    _Pragma("unroll") for (int r = 0; r < 4; ++r) \
    _Pragma("unroll") for (int g = 0; g < 2; ++g) { Sr[r][g] = 0.f; Si[r][g] = 0.f; } }

  // per m: 2 x ds_read_b128 (4 radix rows of this lane's column),
  // 8 CMAC (4 r x 2 q), 2 serial twiddle rotations.
#define RQLOOP(MAC) { \
    float tar = 1.f, tai = 0.f, tbr = 1.f, tbi = 0.f; \
    const float2* bp = lap; \
    _Pragma("unroll 1") \
    for (int m = 0; m < 33; ++m) { \
      float4 d01 = *(const float4*)(bp); \
      float4 d23 = *(const float4*)(bp + 2); \
      MAC(Sr[0][0], Si[0][0], d01.x, d01.y, tar, tai); \
      MAC(Sr[0][1], Si[0][1], d01.x, d01.y, tbr, tbi); \
      MAC(Sr[1][0], Si[1][0], d01.z, d01.w, tar, tai); \
      MAC(Sr[1][1], Si[1][1], d01.z, d01.w, tbr, tbi); \
      MAC(Sr[2][0], Si[2][0], d23.x, d23.y, tar, tai); \
      MAC(Sr[2][1], Si[2][1], d23.x, d23.y, tbr, tbi); \
      MAC(Sr[3][0], Si[3][0], d23.z, d23.w, tar, tai); \
      MAC(Sr[3][1], Si[3][1], d23.z, d23.w, tbr, tbi); \
      { float nt = tar*ca - tai*sa; tai = tar*sa + tai*ca; tar = nt; } \
      { float nt = tbr*cb - tbi*sb; tbi = tbr*sb + tbi*cb; tbr = nt; } \
      bp += MST; \
    } }

  // ---- phase A: forward col-DFT (f-form) ----
  ZERO_S();
  if (act) RQLOOP(CMACF);
  __syncthreads();   // all reads of la complete
  // ---- combine + H-mult, write T into la ([m][j][r], u = 4m+r) ----
  if (act) {
#pragma unroll
    for (int g = 0; g < 2; ++g) {
      if (g == 1 && ph2) continue;
      int q = g ? q2 : qq;
      float sw, cw; sincosf(TWO_PI*(float)q/132.f, &sw, &cw);
      float2 w1v = make_float2(cw, sw);
      float2 w2v = make_float2(cw*cw - sw*sw, 2.f*cw*sw);
      float2 w3v = make_float2(w2v.x*cw - w2v.y*sw, w2v.x*sw + w2v.y*cw);
#define COMBA(s, P1, P2, P3) { \
      int u = q + 33*(s); \
      float xr = Sr[0][g], xi = Si[0][g]; \
      CMACF(xr, xi, Sr[1][g], Si[1][g], TR##P1(w1v), TI##P1(w1v)); \
      CMACF(xr, xi, Sr[2][g], Si[2][g], TR##P2(w2v), TI##P2(w2v)); \
      CMACF(xr, xi, Sr[3][g], Si[3][g], TR##P3(w3v), TI##P3(w3v)); \
      float2 o = make_float2(0.f, 0.f); \
      if (v < NV) { float2 h = Hc[(size_t)v*NP + u]; \
        o = make_float2(xr*h.x - xi*h.y, xr*h.y + xi*h.x); } \
      la[(u>>2)*MST + jj*4 + (u&3)] = o; }
      COMBA(0,0,0,0) COMBA(1,1,2,3) COMBA(2,2,0,2) COMBA(3,3,2,1)
#undef COMBA
    }
  }
  __syncthreads();   // T visible
  // ---- phase B: inverse col-DFT (g-form) ----
  ZERO_S();
  if (act) {
    RQLOOP(CMACG);
#pragma unroll
    for (int g = 0; g < 2; ++g) {
      if (g == 1 && ph2) continue;
      int q = g ? q2 : qq;
      float sw, cw; sincosf(TWO_PI*(float)q/132.f, &sw, &cw);
      float2 w1v = make_float2(cw, sw);
      float2 w2v = make_float2(cw*cw - sw*sw, 2.f*cw*sw);
      float2 w3v = make_float2(w2v.x*cw - w2v.y*sw, w2v.x*sw + w2v.y*cw);
#define COMBB(s, P1, P2, P3) { \
      int n0 = q + 33*(s); \
      float xr = Sr[0][g], xi = Si[0][g]; \
      CMACG(xr, xi, Sr[1][g], Si[1][g], TR##P1(w1v), TI##P1(w1v)); \
      CMACG(xr, xi, Sr[2][g], Si[2][g], TR##P2(w2v), TI##P2(w2v)); \
      CMACG(xr, xi, Sr[3][g], Si[3][g], TR##P3(w3v), TI##P3(w3v)); \
      if (v < NV) U[((size_t)img*NV + v)*NP + n0] = make_float2(xr, xi); }
      COMBB(0,0,0,0) COMBB(1,1,2,3) COMBB(2,2,0,2) COMBB(3,3,2,1)
#undef COMBB
    }
  }
#undef RQLOOP
#undef ZERO_S
}
#undef MST

// S4: two-for-one inverse + radix-4. Row pairs of rho via Hermitian-extended
// spectrum W[v] = Ua_f[v] + i*Ub_f[v] (v 0..131); complex radix-4 IDFT;
// Re -> rho[row], Im -> rho[row+1]. Fill loop j-fast for coalescing;
// (row,row+1) pair fused into one aligned float4 load.
__global__ __launch_bounds__(256, 5) void k_s4(
    const float2* __restrict__ U, float* __restrict__ rho) {
  __shared__ __align__(16) float4 lu[(NP+4)*RLST];
  float2* lu2 = (float2*)lu;
  int tid = threadIdx.x, img = blockIdx.y, row0 = blockIdx.x*28;
  int rmax = NP - row0;
  const float2* Uim = U + (size_t)img*NV*NP;
  for (int e = tid; e < NP*14; e += 256) {
    int j = e % 14, v = e / 14;               // j fast: coalesced float4 runs
    float2 wv = make_float2(0.f, 0.f);
    if (2*j + 1 < rmax) {
      int row = row0 + 2*j;
      if (v < NV) {
        float4 uab = *(const float4*)(Uim + (size_t)v*NP + row);   // (ua, ub)
        wv = make_float2(uab.x - uab.w, uab.y + uab.z);
      } else {
        int vv = NP - v;   // 1..65
        float4 uab = *(const float4*)(Uim + (size_t)vv*NP + row);
        wv = make_float2(uab.x + uab.w, uab.z - uab.y);
      }
    }
    lu2[v*14 + j] = wv;
  }
  __syncthreads();
  int rpg = tid / 33, q = tid - rpg*33;
  int nr = rmax >> 2; if (nr > 7) nr = 7;
  bool act = (tid < 231) && (rpg < nr);
  float s33, c33; sincosf(TWO_PI*(float)q/33.f, &s33, &c33);
  float Sr[4][2], Si[4][2];
#pragma unroll
  for (int r = 0; r < 4; r++) { Sr[r][0]=0.f; Sr[r][1]=0.f; Si[r][0]=0.f; Si[r][1]=0.f; }
  if (act) {
    TWIDDLE3_INIT();
    const float4* bp = lu + rpg;
#pragma unroll 1
    for (int g = 0; g < 11; ++g) {
      STEP41(CMACG, 0, t0r, t0i) ROT3(t0r, t0i)
      STEP41(CMACG, 4, t1r, t1i) ROT3(t1r, t1i)
      STEP41(CMACG, 8, t2r, t2i) ROT3(t2r, t2i)
      bp += 12*RLST;
    }
  }
  if (act) {
    float sw, cw; sincosf(TWO_PI*(float)q/132.f, &sw, &cw);
    float2 w1 = make_float2(cw, sw);
    float2 w2 = make_float2(cw*cw - sw*sw, 2.f*cw*sw);
    float2 w3 = make_float2(w2.x*cw - w2.y*sw, w2.x*sw + w2.y*cw);
    float* rim = rho + (size_t)img*NPP;
    int rbase = row0 + rpg*4;
    const float scale = 1.0f/(float)NPP;
#define COMB4(sidx, P1, P2, P3) { \
    float z0r = Sr[0][0], z0i = Si[0][0], z1r = Sr[0][1], z1i = Si[0][1]; \
    CMACG(z0r, z0i, Sr[1][0], Si[1][0], TR##P1(w1), TI##P1(w1)); \
    CMACG(z1r, z1i, Sr[1][1], Si[1][1], TR##P1(w1), TI##P1(w1)); \
    CMACG(z0r, z0i, Sr[2][0], Si[2][0], TR##P2(w2), TI##P2(w2)); \
    CMACG(z1r, z1i, Sr[2][1], Si[2][1], TR##P2(w2), TI##P2(w2)); \
    CMACG(z0r, z0i, Sr[3][0], Si[3][0], TR##P3(w3), TI##P3(w3)); \
    CMACG(z1r, z1i, Sr[3][1], Si[3][1], TR##P3(w3), TI##P3(w3)); \
    int n1 = q + 33*(sidx); \
    rim[(size_t)(rbase+0)*NP + n1] = z0r*scale; \
    rim[(size_t)(rbase+1)*NP + n1] = z0i*scale; \
    rim[(size_t)(rbase+2)*NP + n1] = z1r*scale; \
    rim[(size_t)(rbase+3)*NP + n1] = z1i*scale; }
    COMB4(0,0,0,0) COMB4(1,1,2,3) COMB4(2,2,0,2) COMB4(3,3,2,1)
#undef COMB4
  }
}
#undef STEP41
#undef RLST

// epilogue: out = gelu( x_up + subpixel 3x3 taps of K over zero-upsampled rho )
__global__ __launch_bounds__(256) void k_epilogue(
    const float* __restrict__ x, const float* __restrict__ wgt,
    const float* __restrict__ rho, float* __restrict__ out) {
  int idx = blockIdx.x * 256 + threadIdx.x;
  int o1 = idx & 255;
  int o0 = (idx >> 8) & 255;
  int img = idx >> 16;
  int c = img & 63;
  int n0 = (o0 + 4) >> 1, n1 = (o1 + 4) >> 1;
  int p0 = o0 & 1, p1 = o1 & 1;
  const float* rim = rho + (size_t)img*NPP;
  int base = n0*NP + n1;
  float r00 = rim[base], r01 = rim[base+1], r10 = rim[base+NP], r11 = rim[base+NP+1];
  const float* w = wgt + c*9;
  float wa = p0 ? (p1 ? w[0] : w[1]) : (p1 ? w[3] : w[4]);
  float wb = p1 ? (p0 ? w[2] : w[5]) : 0.f;
  float wc = p0 ? (p1 ? w[6] : w[7]) : 0.f;
  float wd = (p0 & p1) ? w[8] : 0.f;
  float S = wa*r00 + wb*r01 + wc*r10 + wd*r11;
  float xv = x[(size_t)img*NX*NX + (n0-2)*NX + (n1-2)];
  float z = xv + S;
  out[idx] = 0.5f*z*(1.0f + erff(z*0.70710678118654752f));
}

extern "C" void kernel_launch(void* const* d_in, const int* in_sizes, int n_in,
                              void* d_out, int out_size, void* d_ws, size_t ws_size,
                              hipStream_t stream) {
  const float* x    = (const float*)d_in[0];
  const float* wgt  = (const float*)d_in[1];
  const float* bias = (const float*)d_in[2];
  float* ws = (float*)d_ws;
  float2* H   = (float2*)(ws + OFF_H);
  float2* A   = (float2*)(ws + OFF_A);
  float2* U   = (float2*)(ws + OFF_U);
  float*  rho = ws + OFF_RHO;
  float* out = (float*)d_out;

  k_compute_H<<<dim3((NV*NP + 255)/256, NCH), 256, 0, stream>>>(wgt, bias, H);
  k_s1 <<<dim3(5, NIMG), 256, 0, stream>>>(x, A);      // 5*28 >= 132 rows (2-for-1 radix-4)
  k_s23<<<dim3(5, NIMG), 256, 0, stream>>>(A, H, U);   // [m][j][r] layout, 2xb128/m-step
  k_s4 <<<dim3(5, NIMG), 256, 0, stream>>>(U, rho);    // 5*28 >= 132 rows (2-for-1 radix-4)
  k_epilogue<<<(NIMG*NO*NO)/256, 256, 0, stream>>>(x, wgt, rho, out);
}

// Round 8
// 180.264 us; speedup vs baseline: 1.2628x; 1.2564x over previous
//
#include <hip/hip_runtime.h>
#include <math.h>

#define NP   132
#define NV   67            // Hermitian half-spectrum (0..66), 66 = Nyquist
#define NPP  (NP*NP)       // 17424
#define NCH  64
#define NIMG 256
#define NX   128
#define NO   256
#define TWO_PI 6.2831853071795864769f

// ws layout (floats): H : [NCH][NV][132][2] transfer fn, [c][v][u]
static const size_t OFF_H = 0;

// i-power sign/swap: multiplier i^p (g-form) or (-i)^p (f-form)
#define TR0(t) (t.x)
#define TI0(t) (t.y)
#define TR1(t) (-(t.y))
#define TI1(t) (t.x)
#define TR2(t) (-(t.x))
#define TI2(t) (-(t.y))
#define TR3(t) (t.y)
#define TI3(t) (-(t.x))
#define CMACF(xr, xi, dr, di, TRv, TIv) { xr += (dr)*(TRv) + (di)*(TIv); xi += (di)*(TRv) - (dr)*(TIv); }
#define CMACG(xr, xi, dr, di, TRv, TIv) { xr += (dr)*(TRv) - (di)*(TIv); xi += (di)*(TRv) + (dr)*(TIv); }

__global__ __launch_bounds__(256) void k_compute_H(
    const float* __restrict__ wgt, const float* __restrict__ bias,
    float2* __restrict__ H) {
  int idx = blockIdx.x * 256 + threadIdx.x;   // over NV*NP
  int c = blockIdx.y;
  if (idx >= NV*NP) return;
  int u = idx % NP, v = idx / NP;
  float k[3][3];
#pragma unroll
  for (int i = 0; i < 3; i++)
#pragma unroll
    for (int j = 0; j < 3; j++) k[i][j] = wgt[c*9 + i*3 + j];
  float invW = 0.f;
#pragma unroll
  for (int p0 = -1; p0 <= 1; p0++)
#pragma unroll
    for (int p1 = -1; p1 <= 1; p1++) {
      float s = 0.f;
#pragma unroll
      for (int i = 0; i < 3; i++)
#pragma unroll
        for (int j = 0; j < 3; j++) {
          int i2 = i - 2*p0, j2 = j - 2*p1;
          if (i2 >= 0 && i2 < 3 && j2 >= 0 && j2 < 3) s += k[i][j]*k[i2][j2];
        }
      float ang = TWO_PI * (float)(u*p0 + v*p1) / (float)NP;
      invW += s * cosf(ang);
    }
  float B00 = k[0][0]+k[0][1]+k[1][0]+k[1][1];
  float B10 = k[2][0]+k[2][1];
  float B01 = k[0][2]+k[1][2];
  float B11 = k[2][2];
  float su, cu, sv, cv, suv, cuv;
  sincosf(TWO_PI*(float)u/(float)NP, &su, &cu);
  sincosf(TWO_PI*(float)v/(float)NP, &sv, &cv);
  sincosf(TWO_PI*(float)(u+v)/(float)NP, &suv, &cuv);
  float Bre = B00 + B10*cu + B01*cv + B11*cuv;
  float Bim = -(B10*su + B01*sv + B11*suv);
  float alpha = 1.f/(1.f + expf(9.f - bias[c])) + 1e-5f;
  float d = invW + alpha;
  H[((size_t)c*NV + v)*NP + u] = make_float2((1.f - Bre)/d, (-Bim)/d);
}

// Fully fused: per image (one block, 1024 thr), entirely in LDS:
//   S1 row real-DFT (two-for-one radix-4) -> A[m][v][r]
//   S2 col DFT + H-mult -> T (in place), S3 col IDFT -> U[v][n0]
//   S4 row real-IDFT (two-for-one) -> rho, epilogue -> out.
// R1 (71.9KB): y as float4[132][33] -> Z (same) -> U [v][134]
// R2 (72.3KB): A/T [m][v*4+r] stride 274 -> rho floats [132][136]
__global__ __launch_bounds__(1024, 4) void k_fused(
    const float* __restrict__ x, const float* __restrict__ wgt,
    const float2* __restrict__ H, float* __restrict__ out) {
  __shared__ __align__(16) float2 R1[67*134 + 4];
  __shared__ __align__(16) float2 R2[33*274];
  int tid = threadIdx.x;
  int img = blockIdx.x;
  int c = img & 63;
  const float* xim = x + (size_t)img*NX*NX;
  const float2* Hc = H + (size_t)c*NV*NP;
  float4* yb = (float4*)R1;                 // [n1][rpg] stride 33 f4

  // ---- stage A: y staging (wrap pad 2); rows 4rpg..4rpg+3 packed ----
  for (int e = tid; e < 132*33; e += 1024) {
    int n1 = e % 132, rpg = e / 132;
    int col = (n1 + 126) & 127;
    int r0 = 4*rpg + 126;
    yb[n1*33 + rpg] = make_float4(
        xim[((r0    )&127)*NX + col],
        xim[((r0 + 1)&127)*NX + col],
        xim[((r0 + 2)&127)*NX + col],
        xim[((r0 + 3)&127)*NX + col]);
  }
  __syncthreads();

  // ---- S1: row DFT, two-for-one radix-4, 2 q/lane (phantom q=33 skipped) ----
  {
    bool act = tid < 561;                   // 33 rpg * 17 qq
    int rpg = 0, qq = 0;
    if (act) { rpg = tid/17; qq = tid - rpg*17; }
    int q2 = qq + 17;
    bool ph2 = (q2 >= 33);
    float sa_, ca_, sb_, cb_;
    sincosf(TWO_PI*(float)qq/33.f, &sa_, &ca_);
    sincosf(TWO_PI*(float)q2/33.f, &sb_, &cb_);
    float Sr[4][2][2], Si[4][2][2];
#pragma unroll
    for (int r = 0; r < 4; ++r)
#pragma unroll
      for (int g = 0; g < 2; ++g)
#pragma unroll
        for (int w = 0; w < 2; ++w) { Sr[r][g][w] = 0.f; Si[r][g][w] = 0.f; }
    if (act) {
      const float4* bp = yb + rpg;
      float tar = 1.f, tai = 0.f, tbr = 1.f, tbi = 0.f;
#pragma unroll 1
      for (int m = 0; m < 33; ++m) {
        float4 d0 = bp[0], d1 = bp[33], d2 = bp[66], d3 = bp[99];
#define S1M(r, dd) \
        CMACF(Sr[r][0][0], Si[r][0][0], dd.x, dd.y, tar, tai); \
        CMACF(Sr[r][0][1], Si[r][0][1], dd.z, dd.w, tar, tai); \
        CMACF(Sr[r][1][0], Si[r][1][0], dd.x, dd.y, tbr, tbi); \
        CMACF(Sr[r][1][1], Si[r][1][1], dd.z, dd.w, tbr, tbi);
        S1M(0, d0) S1M(1, d1) S1M(2, d2) S1M(3, d3)
#undef S1M
        { float nt = tar*ca_ - tai*sa_; tai = tar*sa_ + tai*ca_; tar = nt; }
        { float nt = tbr*cb_ - tbi*sb_; tbi = tbr*sb_ + tbi*cb_; tbr = nt; }
        bp += 132;
      }
    }
    __syncthreads();     // all y reads done before Z overwrite
    if (act) {
#pragma unroll
      for (int g = 0; g < 2; ++g) {
        if (g == 1 && ph2) continue;
        int q = g ? q2 : qq;
        float sw, cw; sincosf(TWO_PI*(float)q/132.f, &sw, &cw);
        float2 w1 = make_float2(cw, sw);
        float2 w2 = make_float2(cw*cw - sw*sw, 2.f*cw*sw);
        float2 w3 = make_float2(w2.x*cw - w2.y*sw, w2.x*sw + w2.y*cw);
#define S1C(sidx, P1, P2, P3) { \
        float z0r = Sr[0][g][0], z0i = Si[0][g][0], z1r = Sr[0][g][1], z1i = Si[0][g][1]; \
        CMACF(z0r, z0i, Sr[1][g][0], Si[1][g][0], TR##P1(w1), TI##P1(w1)); \
        CMACF(z1r, z1i, Sr[1][g][1], Si[1][g][1], TR##P1(w1), TI##P1(w1)); \
        CMACF(z0r, z0i, Sr[2][g][0], Si[2][g][0], TR##P2(w2), TI##P2(w2)); \
        CMACF(z1r, z1i, Sr[2][g][1], Si[2][g][1], TR##P2(w2), TI##P2(w2)); \
        CMACF(z0r, z0i, Sr[3][g][0], Si[3][g][0], TR##P3(w3), TI##P3(w3)); \
        CMACF(z1r, z1i, Sr[3][g][1], Si[3][g][1], TR##P3(w3), TI##P3(w3)); \
        yb[(q + 33*(sidx))*33 + rpg] = make_float4(z0r, z0i, z1r, z1i); }
        S1C(0,0,0,0) S1C(1,1,2,3) S1C(2,2,0,2) S1C(3,3,2,1)
#undef S1C
      }
    }
    __syncthreads();     // Z complete
    if (act) {
#pragma unroll
      for (int g = 0; g < 2; ++g) {
        if (g == 1 && ph2) continue;
        int q = g ? q2 : qq;
        float4 Za = yb[q*33 + rpg];
        float4 Zb = yb[((132 - q) % 132)*33 + rpg];
        float4 Zc = yb[(q + 33)*33 + rpg];
        float4 Zd = yb[(99 - q)*33 + rpg];
        float4* A4 = (float4*)&R2[rpg*274 + q*4];
        A4[0] = make_float4(0.5f*(Za.x+Zb.x), 0.5f*(Za.y-Zb.y),
                            0.5f*(Za.y+Zb.y), 0.5f*(Zb.x-Za.x));
        A4[1] = make_float4(0.5f*(Za.z+Zb.z), 0.5f*(Za.w-Zb.w),
                            0.5f*(Za.w+Zb.w), 0.5f*(Zb.z-Za.z));
        float4* B4 = (float4*)&R2[rpg*274 + (q+33)*4];
        B4[0] = make_float4(0.5f*(Zc.x+Zd.x), 0.5f*(Zc.y-Zd.y),
                            0.5f*(Zc.y+Zd.y), 0.5f*(Zd.x-Zc.x));
        B4[1] = make_float4(0.5f*(Zc.z+Zd.z), 0.5f*(Zc.w-Zd.w),
                            0.5f*(Zc.w+Zd.w), 0.5f*(Zd.z-Zc.z));
        if (q == 0) {                       // v = 66 (Nyquist): real parts of Z[66]
          float4 Ze = yb[66*33 + rpg];
          float4* C4 = (float4*)&R2[rpg*274 + 66*4];
          C4[0] = make_float4(Ze.x, 0.f, Ze.y, 0.f);
          C4[1] = make_float4(Ze.z, 0.f, Ze.w, 0.f);
        }
      }
    }
  }
  __syncthreads();       // A ready in R2

  // ---- S2+S3: col DFT + H, col IDFT; 3 q/lane, no phantom ----
  {
    bool act = tid < 737;                   // 67 v * 11 qq
    int v = 0, qq = 0;
    if (act) { v = tid/11; qq = tid - v*11; }
    float sa[3], ca[3];
#pragma unroll
    for (int g = 0; g < 3; ++g)
      sincosf(TWO_PI*(float)(qq + 11*g)/33.f, &sa[g], &ca[g]);
    float2 h[3][4];
    if (act) {
#pragma unroll
      for (int g = 0; g < 3; ++g)
#pragma unroll
        for (int s = 0; s < 4; ++s)
          h[g][s] = Hc[(size_t)v*NP + (qq + 11*g) + 33*s];
    }
    float Sr[4][3], Si[4][3];
#define ZS23() { \
    _Pragma("unroll") for (int r = 0; r < 4; ++r) \
    _Pragma("unroll") for (int g = 0; g < 3; ++g) { Sr[r][g] = 0.f; Si[r][g] = 0.f; } }
#define S23LOOP(MAC) { \
    float tr[3] = {1.f,1.f,1.f}, ti[3] = {0.f,0.f,0.f}; \
    const float2* bp = R2 + v*4; \
    _Pragma("unroll 1") \
    for (int m = 0; m < 33; ++m) { \
      float4 d01 = *(const float4*)(bp); \
      float4 d23 = *(const float4*)(bp + 2); \
      _Pragma("unroll") \
      for (int g = 0; g < 3; ++g) { \
        MAC(Sr[0][g], Si[0][g], d01.x, d01.y, tr[g], ti[g]); \
        MAC(Sr[1][g], Si[1][g], d01.z, d01.w, tr[g], ti[g]); \
        MAC(Sr[2][g], Si[2][g], d23.x, d23.y, tr[g], ti[g]); \
        MAC(Sr[3][g], Si[3][g], d23.z, d23.w, tr[g], ti[g]); \
        float nt = tr[g]*ca[g] - ti[g]*sa[g]; ti[g] = tr[g]*sa[g] + ti[g]*ca[g]; tr[g] = nt; } \
      bp += 274; \
    } }
    ZS23();
    if (act) S23LOOP(CMACF);
    __syncthreads();     // phase-A reads of A done
    if (act) {
#pragma unroll
      for (int g = 0; g < 3; ++g) {
        int q = qq + 11*g;
        float sw, cw; sincosf(TWO_PI*(float)q/132.f, &sw, &cw);
        float2 w1 = make_float2(cw, sw);
        float2 w2 = make_float2(cw*cw - sw*sw, 2.f*cw*sw);
        float2 w3 = make_float2(w2.x*cw - w2.y*sw, w2.x*sw + w2.y*cw);
#define S23A(sidx, P1, P2, P3) { \
        int u = q + 33*(sidx); \
        float xr = Sr[0][g], xi = Si[0][g]; \
        CMACF(xr, xi, Sr[1][g], Si[1][g], TR##P1(w1), TI##P1(w1)); \
        CMACF(xr, xi, Sr[2][g], Si[2][g], TR##P2(w2), TI##P2(w2)); \
        CMACF(xr, xi, Sr[3][g], Si[3][g], TR##P3(w3), TI##P3(w3)); \
        float2 hh = h[g][sidx]; \
        R2[(u>>2)*274 + v*4 + (u&3)] = make_float2(xr*hh.x - xi*hh.y, xr*hh.y + xi*hh.x); }
        S23A(0,0,0,0) S23A(1,1,2,3) S23A(2,2,0,2) S23A(3,3,2,1)
#undef S23A
      }
    }
    __syncthreads();     // T visible
    ZS23();
    if (act) {
      S23LOOP(CMACG);
#pragma unroll
      for (int g = 0; g < 3; ++g) {
        int q = qq + 11*g;
        float sw, cw; sincosf(TWO_PI*(float)q/132.f, &sw, &cw);
        float2 w1 = make_float2(cw, sw);
        float2 w2 = make_float2(cw*cw - sw*sw, 2.f*cw*sw);
        float2 w3 = make_float2(w2.x*cw - w2.y*sw, w2.x*sw + w2.y*cw);
#define S23B(sidx, P1, P2, P3) { \
        int n0 = q + 33*(sidx); \
        float xr = Sr[0][g], xi = Si[0][g]; \
        CMACG(xr, xi, Sr[1][g], Si[1][g], TR##P1(w1), TI##P1(w1)); \
        CMACG(xr, xi, Sr[2][g], Si[2][g], TR##P2(w2), TI##P2(w2)); \
        CMACG(xr, xi, Sr[3][g], Si[3][g], TR##P3(w3), TI##P3(w3)); \
        R1[v*134 + n0] = make_float2(xr, xi); }
        S23B(0,0,0,0) S23B(1,1,2,3) S23B(2,2,0,2) S23B(3,3,2,1)
#undef S23B
      }
    }
#undef S23LOOP
#undef ZS23
  }
  __syncthreads();       // U ready in R1; T dead

  // ---- S4: row real-IDFT via Hermitian-extended W, 3 q/lane, rho -> R2 ----
  {
    bool act = tid < 726;                   // 66 rowpairs * 11 qq
    int j = 0, qq = 0;
    if (act) { j = tid/11; qq = tid - j*11; }
    float sa[3], ca[3];
#pragma unroll
    for (int g = 0; g < 3; ++g)
      sincosf(TWO_PI*(float)(qq + 11*g)/33.f, &sa[g], &ca[g]);
    float Sr[4][3], Si[4][3];
#pragma unroll
    for (int r = 0; r < 4; ++r)
#pragma unroll
      for (int g = 0; g < 3; ++g) { Sr[r][g] = 0.f; Si[r][g] = 0.f; }
    if (act) {
      const float2* Up = R1 + 2*j;
      float tr[3] = {1.f,1.f,1.f}, ti[3] = {0.f,0.f,0.f};
#pragma unroll 1
      for (int m = 0; m < 33; ++m) {
#pragma unroll
        for (int r = 0; r < 4; ++r) {
          int v4 = 4*m + r;
          int vv = (v4 <= 66) ? v4 : (132 - v4);
          float sg = (v4 <= 66) ? 1.f : -1.f;
          float4 f = *(const float4*)(Up + vv*134);
          float Wr = f.x - sg*f.w;
          float Wi = sg*f.y + f.z;
#pragma unroll
          for (int g = 0; g < 3; ++g)
            CMACG(Sr[r][g], Si[r][g], Wr, Wi, tr[g], ti[g]);
        }
#pragma unroll
        for (int g = 0; g < 3; ++g) {
          float nt = tr[g]*ca[g] - ti[g]*sa[g]; ti[g] = tr[g]*sa[g] + ti[g]*ca[g]; tr[g] = nt;
        }
      }
      float* rho2 = (float*)R2;
      const float scale = 1.0f/(float)NPP;
#pragma unroll
      for (int g = 0; g < 3; ++g) {
        int q = qq + 11*g;
        float sw, cw; sincosf(TWO_PI*(float)q/132.f, &sw, &cw);
        float2 w1 = make_float2(cw, sw);
        float2 w2 = make_float2(cw*cw - sw*sw, 2.f*cw*sw);
        float2 w3 = make_float2(w2.x*cw - w2.y*sw, w2.x*sw + w2.y*cw);
#define S4C(sidx, P1, P2, P3) { \
        int n1 = q + 33*(sidx); \
        float zr = Sr[0][g], zi = Si[0][g]; \
        CMACG(zr, zi, Sr[1][g], Si[1][g], TR##P1(w1), TI##P1(w1)); \
        CMACG(zr, zi, Sr[2][g], Si[2][g], TR##P2(w2), TI##P2(w2)); \
        CMACG(zr, zi, Sr[3][g], Si[3][g], TR##P3(w3), TI##P3(w3)); \
        rho2[(2*j)*136 + n1] = zr*scale; \
        rho2[(2*j+1)*136 + n1] = zi*scale; }
        S4C(0,0,0,0) S4C(1,1,2,3) S4C(2,2,0,2) S4C(3,3,2,1)
#undef S4C
      }
    }
  }
  __syncthreads();       // rho ready

  // ---- epilogue: out = gelu(x_up + subpixel taps of K over rho) ----
  {
    const float* rho2 = (const float*)R2;
    const float* w = wgt + c*9;
    float k0=w[0], k1=w[1], k2=w[2], k3=w[3], k4=w[4], k5=w[5], k6=w[6], k7=w[7], k8=w[8];
    float* outim = out + (size_t)img*NO*NO;
    for (int e = tid; e < NO*NO; e += 1024) {
      int o1 = e & 255, o0 = e >> 8;
      int n0 = (o0 + 4) >> 1, n1 = (o1 + 4) >> 1;
      int p0 = o0 & 1, p1 = o1 & 1;
      int base = n0*136 + n1;
      float r00 = rho2[base],     r01 = rho2[base+1];
      float r10 = rho2[base+136], r11 = rho2[base+137];
      float wa = p0 ? (p1 ? k0 : k1) : (p1 ? k3 : k4);
      float wb = p1 ? (p0 ? k2 : k5) : 0.f;
      float wc = p0 ? (p1 ? k6 : k7) : 0.f;
      float wd = (p0 & p1) ? k8 : 0.f;
      float S = wa*r00 + wb*r01 + wc*r10 + wd*r11;
      float xv = xim[(n0-2)*NX + (n1-2)];
      float z = xv + S;
      outim[e] = 0.5f*z*(1.0f + erff(z*0.70710678118654752f));
    }
  }
}

extern "C" void kernel_launch(void* const* d_in, const int* in_sizes, int n_in,
                              void* d_out, int out_size, void* d_ws, size_t ws_size,
                              hipStream_t stream) {
  const float* x    = (const float*)d_in[0];
  const float* wgt  = (const float*)d_in[1];
  const float* bias = (const float*)d_in[2];
  float* ws = (float*)d_ws;
  float2* H = (float2*)(ws + OFF_H);
  float* out = (float*)d_out;

  k_compute_H<<<dim3((NV*NP + 255)/256, NCH), 256, 0, stream>>>(wgt, bias, H);
  k_fused<<<dim3(NIMG), 1024, 0, stream>>>(x, wgt, H, out);   // 1 image/block, 1 block/CU
}

// Round 9
// 155.409 us; speedup vs baseline: 1.4648x; 1.1599x over previous
//
#include <hip/hip_runtime.h>
#include <math.h>

#define NP   132
#define NV   67            // Hermitian half-spectrum (0..66), 66 = Nyquist
#define NPP  (NP*NP)       // 17424
#define NCH  64
#define NIMG 256
#define NX   128
#define NO   256
#define TWO_PI 6.2831853071795864769f

// ws layout (floats): H : [NCH][NV][132][2] transfer fn, [c][v][u]
static const size_t OFF_H = 0;

// i-power sign/swap: multiplier i^p (g-form) or (-i)^p (f-form)
#define TR0(t) (t.x)
#define TI0(t) (t.y)
#define TR1(t) (-(t.y))
#define TI1(t) (t.x)
#define TR2(t) (-(t.x))
#define TI2(t) (-(t.y))
#define TR3(t) (t.y)
#define TI3(t) (-(t.x))
#define CMACF(xr, xi, dr, di, TRv, TIv) { xr += (dr)*(TRv) + (di)*(TIv); xi += (di)*(TRv) - (dr)*(TIv); }
#define CMACG(xr, xi, dr, di, TRv, TIv) { xr += (dr)*(TRv) - (di)*(TIv); xi += (di)*(TRv) + (dr)*(TIv); }

__global__ __launch_bounds__(256) void k_compute_H(
    const float* __restrict__ wgt, const float* __restrict__ bias,
    float2* __restrict__ H) {
  int idx = blockIdx.x * 256 + threadIdx.x;   // over NV*NP
  int c = blockIdx.y;
  if (idx >= NV*NP) return;
  int u = idx % NP, v = idx / NP;
  float k[3][3];
#pragma unroll
  for (int i = 0; i < 3; i++)
#pragma unroll
    for (int j = 0; j < 3; j++) k[i][j] = wgt[c*9 + i*3 + j];
  float invW = 0.f;
#pragma unroll
  for (int p0 = -1; p0 <= 1; p0++)
#pragma unroll
    for (int p1 = -1; p1 <= 1; p1++) {
      float s = 0.f;
#pragma unroll
      for (int i = 0; i < 3; i++)
#pragma unroll
        for (int j = 0; j < 3; j++) {
          int i2 = i - 2*p0, j2 = j - 2*p1;
          if (i2 >= 0 && i2 < 3 && j2 >= 0 && j2 < 3) s += k[i][j]*k[i2][j2];
        }
      float ang = TWO_PI * (float)(u*p0 + v*p1) / (float)NP;
      invW += s * cosf(ang);
    }
  float B00 = k[0][0]+k[0][1]+k[1][0]+k[1][1];
  float B10 = k[2][0]+k[2][1];
  float B01 = k[0][2]+k[1][2];
  float B11 = k[2][2];
  float su, cu, sv, cv, suv, cuv;
  sincosf(TWO_PI*(float)u/(float)NP, &su, &cu);
  sincosf(TWO_PI*(float)v/(float)NP, &sv, &cv);
  sincosf(TWO_PI*(float)(u+v)/(float)NP, &suv, &cuv);
  float Bre = B00 + B10*cu + B01*cv + B11*cuv;
  float Bim = -(B10*su + B01*sv + B11*suv);
  float alpha = 1.f/(1.f + expf(9.f - bias[c])) + 1e-5f;
  float d = invW + alpha;
  H[((size_t)c*NV + v)*NP + u] = make_float2((1.f - Bre)/d, (-Bim)/d);
}

// Fully fused: per image (one block, 1024 thr), entirely in LDS:
//   S1 row real-DFT (two-for-one radix-4) -> A[m][v][r]
//   S2 col DFT + H-mult -> T (in place), S3 col IDFT -> U[v][n0]
//   S4 row real-IDFT (two-for-one) -> rho, epilogue -> out.
// S23/S4 m-loops use radix-3 split of the 33-sum (m = 3t+s): the 3 q's per
// lane (q = qq+11g) share the SS[s][r] sub-sums -> 2.5x CMAC cut.
// R1 (71.9KB): y as float4[132][33] -> Z (same) -> U [v][134]
// R2 (72.3KB): A/T [m][v*4+r] stride 274 -> rho floats [132][136]
__global__ __launch_bounds__(1024, 4) void k_fused(
    const float* __restrict__ x, const float* __restrict__ wgt,
    const float2* __restrict__ H, float* __restrict__ out) {
  __shared__ __align__(16) float2 R1[67*134 + 4];
  __shared__ __align__(16) float2 R2[33*274];
  int tid = threadIdx.x;
  int img = blockIdx.x;
  int c = img & 63;
  const float* xim = x + (size_t)img*NX*NX;
  const float2* Hc = H + (size_t)c*NV*NP;
  float4* yb = (float4*)R1;                 // [n1][rpg] stride 33 f4

  // ---- stage A: y staging (wrap pad 2); rows 4rpg..4rpg+3 packed ----
  for (int e = tid; e < 132*33; e += 1024) {
    int n1 = e % 132, rpg = e / 132;
    int col = (n1 + 126) & 127;
    int r0 = 4*rpg + 126;
    yb[n1*33 + rpg] = make_float4(
        xim[((r0    )&127)*NX + col],
        xim[((r0 + 1)&127)*NX + col],
        xim[((r0 + 2)&127)*NX + col],
        xim[((r0 + 3)&127)*NX + col]);
  }
  __syncthreads();

  // ---- S1: row DFT, two-for-one radix-4, 2 q/lane (phantom q=33 skipped) ----
  {
    bool act = tid < 561;                   // 33 rpg * 17 qq
    int rpg = 0, qq = 0;
    if (act) { rpg = tid/17; qq = tid - rpg*17; }
    int q2 = qq + 17;
    bool ph2 = (q2 >= 33);
    float sa_, ca_, sb_, cb_;
    sincosf(TWO_PI*(float)qq/33.f, &sa_, &ca_);
    sincosf(TWO_PI*(float)q2/33.f, &sb_, &cb_);
    float Sr[4][2][2], Si[4][2][2];
#pragma unroll
    for (int r = 0; r < 4; ++r)
#pragma unroll
      for (int g = 0; g < 2; ++g)
#pragma unroll
        for (int w = 0; w < 2; ++w) { Sr[r][g][w] = 0.f; Si[r][g][w] = 0.f; }
    if (act) {
      const float4* bp = yb + rpg;
      float tar = 1.f, tai = 0.f, tbr = 1.f, tbi = 0.f;
#pragma unroll 1
      for (int m = 0; m < 33; ++m) {
        float4 d0 = bp[0], d1 = bp[33], d2 = bp[66], d3 = bp[99];
#define S1M(r, dd) \
        CMACF(Sr[r][0][0], Si[r][0][0], dd.x, dd.y, tar, tai); \
        CMACF(Sr[r][0][1], Si[r][0][1], dd.z, dd.w, tar, tai); \
        CMACF(Sr[r][1][0], Si[r][1][0], dd.x, dd.y, tbr, tbi); \
        CMACF(Sr[r][1][1], Si[r][1][1], dd.z, dd.w, tbr, tbi);
        S1M(0, d0) S1M(1, d1) S1M(2, d2) S1M(3, d3)
#undef S1M
        { float nt = tar*ca_ - tai*sa_; tai = tar*sa_ + tai*ca_; tar = nt; }
        { float nt = tbr*cb_ - tbi*sb_; tbi = tbr*sb_ + tbi*cb_; tbr = nt; }
        bp += 132;
      }
    }
    __syncthreads();     // all y reads done before Z overwrite
    if (act) {
#pragma unroll
      for (int g = 0; g < 2; ++g) {
        if (g == 1 && ph2) continue;
        int q = g ? q2 : qq;
        float sw, cw; sincosf(TWO_PI*(float)q/132.f, &sw, &cw);
        float2 w1 = make_float2(cw, sw);
        float2 w2 = make_float2(cw*cw - sw*sw, 2.f*cw*sw);
        float2 w3 = make_float2(w2.x*cw - w2.y*sw, w2.x*sw + w2.y*cw);
#define S1C(sidx, P1, P2, P3) { \
        float z0r = Sr[0][g][0], z0i = Si[0][g][0], z1r = Sr[0][g][1], z1i = Si[0][g][1]; \
        CMACF(z0r, z0i, Sr[1][g][0], Si[1][g][0], TR##P1(w1), TI##P1(w1)); \
        CMACF(z1r, z1i, Sr[1][g][1], Si[1][g][1], TR##P1(w1), TI##P1(w1)); \
        CMACF(z0r, z0i, Sr[2][g][0], Si[2][g][0], TR##P2(w2), TI##P2(w2)); \
        CMACF(z1r, z1i, Sr[2][g][1], Si[2][g][1], TR##P2(w2), TI##P2(w2)); \
        CMACF(z0r, z0i, Sr[3][g][0], Si[3][g][0], TR##P3(w3), TI##P3(w3)); \
        CMACF(z1r, z1i, Sr[3][g][1], Si[3][g][1], TR##P3(w3), TI##P3(w3)); \
        yb[(q + 33*(sidx))*33 + rpg] = make_float4(z0r, z0i, z1r, z1i); }
        S1C(0,0,0,0) S1C(1,1,2,3) S1C(2,2,0,2) S1C(3,3,2,1)
#undef S1C
      }
    }
    __syncthreads();     // Z complete
    if (act) {
#pragma unroll
      for (int g = 0; g < 2; ++g) {
        if (g == 1 && ph2) continue;
        int q = g ? q2 : qq;
        float4 Za = yb[q*33 + rpg];
        float4 Zb = yb[((132 - q) % 132)*33 + rpg];
        float4 Zc = yb[(q + 33)*33 + rpg];
        float4 Zd = yb[(99 - q)*33 + rpg];
        float4* A4 = (float4*)&R2[rpg*274 + q*4];
        A4[0] = make_float4(0.5f*(Za.x+Zb.x), 0.5f*(Za.y-Zb.y),
                            0.5f*(Za.y+Zb.y), 0.5f*(Zb.x-Za.x));
        A4[1] = make_float4(0.5f*(Za.z+Zb.z), 0.5f*(Za.w-Zb.w),
                            0.5f*(Za.w+Zb.w), 0.5f*(Zb.z-Za.z));
        float4* B4 = (float4*)&R2[rpg*274 + (q+33)*4];
        B4[0] = make_float4(0.5f*(Zc.x+Zd.x), 0.5f*(Zc.y-Zd.y),
                            0.5f*(Zc.y+Zd.y), 0.5f*(Zd.x-Zc.x));
        B4[1] = make_float4(0.5f*(Zc.z+Zd.z), 0.5f*(Zc.w-Zd.w),
                            0.5f*(Zc.w+Zd.w), 0.5f*(Zd.z-Zc.z));
        if (q == 0) {                       // v = 66 (Nyquist): real parts of Z[66]
          float4 Ze = yb[66*33 + rpg];
          float4* C4 = (float4*)&R2[rpg*274 + 66*4];
          C4[0] = make_float4(Ze.x, 0.f, Ze.y, 0.f);
          C4[1] = make_float4(Ze.z, 0.f, Ze.w, 0.f);
        }
      }
    }
  }
  __syncthreads();       // A ready in R2

  // ---- S2+S3: col DFT + H, col IDFT; 3 q/lane (q = qq+11g), radix-3 m-split ----
  {
    bool act = tid < 737;                   // 67 v * 11 qq
    int v = 0, qq = 0;
    if (act) { v = tid/11; qq = tid - v*11; }
    float s11, c11; sincosf(TWO_PI*(float)qq/11.f, &s11, &c11);
    float s33q, c33q; sincosf(TWO_PI*(float)qq/33.f, &s33q, &c33q);
    // w33 per g: rotate base by e^{i 2pi g/3}
    const float CG = -0.5f, SG = 0.86602540378443864676f;
    float c33g[3], s33g[3];
    c33g[0] = c33q;               s33g[0] = s33q;
    c33g[1] = c33q*CG - s33q*SG;  s33g[1] = s33q*CG + c33q*SG;
    c33g[2] = c33q*CG + s33q*SG;  s33g[2] = s33q*CG - c33q*SG;
    float SSr[3][4], SSi[3][4];   // [s][r] shared sub-sums
    float Sr[4][3], Si[4][3];     // [r][g]
    float2 h[3][4];
#define ZSS() { \
    _Pragma("unroll") for (int s = 0; s < 3; ++s) \
    _Pragma("unroll") for (int r = 0; r < 4; ++r) { SSr[s][r] = 0.f; SSi[s][r] = 0.f; } }
#define S23TLOOP(MAC) { \
    float tr = 1.f, ti = 0.f; \
    const float2* bp = R2 + v*4; \
    _Pragma("unroll 1") \
    for (int t = 0; t < 11; ++t) { \
      _Pragma("unroll") \
      for (int s = 0; s < 3; ++s) { \
        float4 d01 = *(const float4*)(bp + s*274); \
        float4 d23 = *(const float4*)(bp + s*274 + 2); \
        MAC(SSr[s][0], SSi[s][0], d01.x, d01.y, tr, ti); \
        MAC(SSr[s][1], SSi[s][1], d01.z, d01.w, tr, ti); \
        MAC(SSr[s][2], SSi[s][2], d23.x, d23.y, tr, ti); \
        MAC(SSr[s][3], SSi[s][3], d23.z, d23.w, tr, ti); } \
      { float nt = tr*c11 - ti*s11; ti = tr*s11 + ti*c11; tr = nt; } \
      bp += 3*274; \
    } }
#define S23COMB(MAC) { \
    _Pragma("unroll") \
    for (int g = 0; g < 3; ++g) { \
      float cA = c33g[g], sA = s33g[g]; \
      float cB = cA*cA - sA*sA, sB = 2.f*cA*sA; \
      _Pragma("unroll") \
      for (int r = 0; r < 4; ++r) { \
        float xr = SSr[0][r], xi = SSi[0][r]; \
        MAC(xr, xi, SSr[1][r], SSi[1][r], cA, sA); \
        MAC(xr, xi, SSr[2][r], SSi[2][r], cB, sB); \
        Sr[r][g] = xr; Si[r][g] = xi; } } }
    // ---- phase A: forward col-DFT ----
    ZSS();
    if (act) {
      S23TLOOP(CMACF);
      S23COMB(CMACF);
#pragma unroll
      for (int g = 0; g < 3; ++g)
#pragma unroll
        for (int s = 0; s < 4; ++s)
          h[g][s] = Hc[(size_t)v*NP + (qq + 11*g) + 33*s];
    }
    __syncthreads();     // phase-A reads of A done
    if (act) {
#pragma unroll
      for (int g = 0; g < 3; ++g) {
        int q = qq + 11*g;
        float sw, cw; sincosf(TWO_PI*(float)q/132.f, &sw, &cw);
        float2 w1 = make_float2(cw, sw);
        float2 w2 = make_float2(cw*cw - sw*sw, 2.f*cw*sw);
        float2 w3 = make_float2(w2.x*cw - w2.y*sw, w2.x*sw + w2.y*cw);
#define S23A(sidx, P1, P2, P3) { \
        int u = q + 33*(sidx); \
        float xr = Sr[0][g], xi = Si[0][g]; \
        CMACF(xr, xi, Sr[1][g], Si[1][g], TR##P1(w1), TI##P1(w1)); \
        CMACF(xr, xi, Sr[2][g], Si[2][g], TR##P2(w2), TI##P2(w2)); \
        CMACF(xr, xi, Sr[3][g], Si[3][g], TR##P3(w3), TI##P3(w3)); \
        float2 hh = h[g][sidx]; \
        R2[(u>>2)*274 + v*4 + (u&3)] = make_float2(xr*hh.x - xi*hh.y, xr*hh.y + xi*hh.x); }
        S23A(0,0,0,0) S23A(1,1,2,3) S23A(2,2,0,2) S23A(3,3,2,1)
#undef S23A
      }
    }
    __syncthreads();     // T visible
    // ---- phase B: inverse col-DFT ----
    ZSS();
    if (act) {
      S23TLOOP(CMACG);
      S23COMB(CMACG);
#pragma unroll
      for (int g = 0; g < 3; ++g) {
        int q = qq + 11*g;
        float sw, cw; sincosf(TWO_PI*(float)q/132.f, &sw, &cw);
        float2 w1 = make_float2(cw, sw);
        float2 w2 = make_float2(cw*cw - sw*sw, 2.f*cw*sw);
        float2 w3 = make_float2(w2.x*cw - w2.y*sw, w2.x*sw + w2.y*cw);
#define S23B(sidx, P1, P2, P3) { \
        int n0 = q + 33*(sidx); \
        float xr = Sr[0][g], xi = Si[0][g]; \
        CMACG(xr, xi, Sr[1][g], Si[1][g], TR##P1(w1), TI##P1(w1)); \
        CMACG(xr, xi, Sr[2][g], Si[2][g], TR##P2(w2), TI##P2(w2)); \
        CMACG(xr, xi, Sr[3][g], Si[3][g], TR##P3(w3), TI##P3(w3)); \
        R1[v*134 + n0] = make_float2(xr, xi); }
        S23B(0,0,0,0) S23B(1,1,2,3) S23B(2,2,0,2) S23B(3,3,2,1)
#undef S23B
      }
    }
#undef S23TLOOP
#undef S23COMB
#undef ZSS
  }
  __syncthreads();       // U ready in R1; T dead

  // ---- S4: row real-IDFT via Hermitian-extended W, 3 q/lane, radix-3 m-split ----
  {
    bool act = tid < 726;                   // 66 rowpairs * 11 qq
    int j = 0, qq = 0;
    if (act) { j = tid/11; qq = tid - j*11; }
    float s11, c11; sincosf(TWO_PI*(float)qq/11.f, &s11, &c11);
    float s33q, c33q; sincosf(TWO_PI*(float)qq/33.f, &s33q, &c33q);
    const float CG = -0.5f, SG = 0.86602540378443864676f;
    float c33g[3], s33g[3];
    c33g[0] = c33q;               s33g[0] = s33q;
    c33g[1] = c33q*CG - s33q*SG;  s33g[1] = s33q*CG + c33q*SG;
    c33g[2] = c33q*CG + s33q*SG;  s33g[2] = s33q*CG - c33q*SG;
    float SSr[3][4], SSi[3][4];
#pragma unroll
    for (int s = 0; s < 3; ++s)
#pragma unroll
      for (int r = 0; r < 4; ++r) { SSr[s][r] = 0.f; SSi[s][r] = 0.f; }
    if (act) {
      const float2* Up = R1 + 2*j;
      float tr = 1.f, ti = 0.f;
#pragma unroll 1
      for (int t = 0; t < 11; ++t) {
#pragma unroll
        for (int s = 0; s < 3; ++s)
#pragma unroll
          for (int r = 0; r < 4; ++r) {
            int v4 = 12*t + 4*s + r;
            int vv = (v4 <= 66) ? v4 : (132 - v4);
            float sg = (v4 <= 66) ? 1.f : -1.f;
            float4 f = *(const float4*)(Up + vv*134);
            float Wr = f.x - sg*f.w;
            float Wi = sg*f.y + f.z;
            CMACG(SSr[s][r], SSi[s][r], Wr, Wi, tr, ti);
          }
        { float nt = tr*c11 - ti*s11; ti = tr*s11 + ti*c11; tr = nt; }
      }
      float Sr[4][3], Si[4][3];
#pragma unroll
      for (int g = 0; g < 3; ++g) {
        float cA = c33g[g], sA = s33g[g];
        float cB = cA*cA - sA*sA, sB = 2.f*cA*sA;
#pragma unroll
        for (int r = 0; r < 4; ++r) {
          float xr = SSr[0][r], xi = SSi[0][r];
          CMACG(xr, xi, SSr[1][r], SSi[1][r], cA, sA);
          CMACG(xr, xi, SSr[2][r], SSi[2][r], cB, sB);
          Sr[r][g] = xr; Si[r][g] = xi;
        }
      }
      float* rho2 = (float*)R2;
      const float scale = 1.0f/(float)NPP;
#pragma unroll
      for (int g = 0; g < 3; ++g) {
        int q = qq + 11*g;
        float sw, cw; sincosf(TWO_PI*(float)q/132.f, &sw, &cw);
        float2 w1 = make_float2(cw, sw);
        float2 w2 = make_float2(cw*cw - sw*sw, 2.f*cw*sw);
        float2 w3 = make_float2(w2.x*cw - w2.y*sw, w2.x*sw + w2.y*cw);
#define S4C(sidx, P1, P2, P3) { \
        int n1 = q + 33*(sidx); \
        float zr = Sr[0][g], zi = Si[0][g]; \
        CMACG(zr, zi, Sr[1][g], Si[1][g], TR##P1(w1), TI##P1(w1)); \
        CMACG(zr, zi, Sr[2][g], Si[2][g], TR##P2(w2), TI##P2(w2)); \
        CMACG(zr, zi, Sr[3][g], Si[3][g], TR##P3(w3), TI##P3(w3)); \
        rho2[(2*j)*136 + n1] = zr*scale; \
        rho2[(2*j+1)*136 + n1] = zi*scale; }
        S4C(0,0,0,0) S4C(1,1,2,3) S4C(2,2,0,2) S4C(3,3,2,1)
#undef S4C
      }
    }
  }
  __syncthreads();       // rho ready

  // ---- epilogue: out = gelu(x_up + subpixel taps of K over rho) ----
  {
    const float* rho2 = (const float*)R2;
    const float* w = wgt + c*9;
    float k0=w[0], k1=w[1], k2=w[2], k3=w[3], k4=w[4], k5=w[5], k6=w[6], k7=w[7], k8=w[8];
    float* outim = out + (size_t)img*NO*NO;
    for (int e = tid; e < NO*NO; e += 1024) {
      int o1 = e & 255, o0 = e >> 8;
      int n0 = (o0 + 4) >> 1, n1 = (o1 + 4) >> 1;
      int p0 = o0 & 1, p1 = o1 & 1;
      int base = n0*136 + n1;
      float r00 = rho2[base],     r01 = rho2[base+1];
      float r10 = rho2[base+136], r11 = rho2[base+137];
      float wa = p0 ? (p1 ? k0 : k1) : (p1 ? k3 : k4);
      float wb = p1 ? (p0 ? k2 : k5) : 0.f;
      float wc = p0 ? (p1 ? k6 : k7) : 0.f;
      float wd = (p0 & p1) ? k8 : 0.f;
      float S = wa*r00 + wb*r01 + wc*r10 + wd*r11;
      float xv = xim[(n0-2)*NX + (n1-2)];
      float z = xv + S;
      outim[e] = 0.5f*z*(1.0f + erff(z*0.70710678118654752f));
    }
  }
}

extern "C" void kernel_launch(void* const* d_in, const int* in_sizes, int n_in,
                              void* d_out, int out_size, void* d_ws, size_t ws_size,
                              hipStream_t stream) {
  const float* x    = (const float*)d_in[0];
  const float* wgt  = (const float*)d_in[1];
  const float* bias = (const float*)d_in[2];
  float* ws = (float*)d_ws;
  float2* H = (float2*)(ws + OFF_H);
  float* out = (float*)d_out;

  k_compute_H<<<dim3((NV*NP + 255)/256, NCH), 256, 0, stream>>>(wgt, bias, H);
  k_fused<<<dim3(NIMG), 1024, 0, stream>>>(x, wgt, H, out);   // 1 image/block, 1 block/CU
}

// Round 10
// 143.993 us; speedup vs baseline: 1.5809x; 1.0793x over previous
//
#include <hip/hip_runtime.h>
#include <math.h>

#define NP   132
#define NV   67            // Hermitian half-spectrum (0..66), 66 = Nyquist
#define NPP  (NP*NP)       // 17424
#define NCH  64
#define NIMG 256
#define NX   128
#define NO   256
#define TWO_PI 6.2831853071795864769f

// ws layout (floats): H : [NCH][NV][132][2] transfer fn, [c][v][u]
static const size_t OFF_H = 0;

// i-power sign/swap: multiplier i^p (g-form) or (-i)^p (f-form)
#define TR0(t) (t.x)
#define TI0(t) (t.y)
#define TR1(t) (-(t.y))
#define TI1(t) (t.x)
#define TR2(t) (-(t.x))
#define TI2(t) (-(t.y))
#define TR3(t) (t.y)
#define TI3(t) (-(t.x))
#define CMACF(xr, xi, dr, di, TRv, TIv) { xr += (dr)*(TRv) + (di)*(TIv); xi += (di)*(TRv) - (dr)*(TIv); }
#define CMACG(xr, xi, dr, di, TRv, TIv) { xr += (dr)*(TRv) - (di)*(TIv); xi += (di)*(TRv) + (dr)*(TIv); }

__global__ __launch_bounds__(256) void k_compute_H(
    const float* __restrict__ wgt, const float* __restrict__ bias,
    float2* __restrict__ H) {
  int idx = blockIdx.x * 256 + threadIdx.x;   // over NV*NP
  int c = blockIdx.y;
  if (idx >= NV*NP) return;
  int u = idx % NP, v = idx / NP;
  float k[3][3];
#pragma unroll
  for (int i = 0; i < 3; i++)
#pragma unroll
    for (int j = 0; j < 3; j++) k[i][j] = wgt[c*9 + i*3 + j];
  float invW = 0.f;
#pragma unroll
  for (int p0 = -1; p0 <= 1; p0++)
#pragma unroll
    for (int p1 = -1; p1 <= 1; p1++) {
      float s = 0.f;
#pragma unroll
      for (int i = 0; i < 3; i++)
#pragma unroll
        for (int j = 0; j < 3; j++) {
          int i2 = i - 2*p0, j2 = j - 2*p1;
          if (i2 >= 0 && i2 < 3 && j2 >= 0 && j2 < 3) s += k[i][j]*k[i2][j2];
        }
      float ang = TWO_PI * (float)(u*p0 + v*p1) / (float)NP;
      invW += s * cosf(ang);
    }
  float B00 = k[0][0]+k[0][1]+k[1][0]+k[1][1];
  float B10 = k[2][0]+k[2][1];
  float B01 = k[0][2]+k[1][2];
  float B11 = k[2][2];
  float su, cu, sv, cv, suv, cuv;
  sincosf(TWO_PI*(float)u/(float)NP, &su, &cu);
  sincosf(TWO_PI*(float)v/(float)NP, &sv, &cv);
  sincosf(TWO_PI*(float)(u+v)/(float)NP, &suv, &cuv);
  float Bre = B00 + B10*cu + B01*cv + B11*cuv;
  float Bim = -(B10*su + B01*sv + B11*suv);
  float alpha = 1.f/(1.f + expf(9.f - bias[c])) + 1e-5f;
  float d = invW + alpha;
  H[((size_t)c*NV + v)*NP + u] = make_float2((1.f - Bre)/d, (-Bim)/d);
}

// Fully fused per image (one block, 1024 thr), all intermediates in LDS.
// All DFT stages use radix-4 x radix-3: per lane 3 q's (q = qq+11g) share
// SS[s][r] sub-sums (m = 3t+s, n = 4m+r). Per-g w33/w132 twiddles derived
// from one sincosf by constant rotations e^{2pi i g/3} / e^{2pi i g/12}.
// R1 (71.9KB): y/Z [j=rowpair][n1] stride 134 -> U [v][134] -> rho [132][136] floats
// R2 (72.3KB): A/T [m][v*4+r] stride 274 -> W [j][v4] stride 134
__global__ __launch_bounds__(1024, 4) void k_fused(
    const float* __restrict__ x, const float* __restrict__ wgt,
    const float2* __restrict__ H, float* __restrict__ out) {
  __shared__ __align__(16) float2 R1[67*134 + 4];
  __shared__ __align__(16) float2 R2[33*274];
  int tid = threadIdx.x;
  int img = blockIdx.x;
  int c = img & 63;
  const float* xim = x + (size_t)img*NX*NX;
  const float2* Hc = H + (size_t)c*NV*NP;
  const float CG = -0.5f,                  SG = 0.86602540378443864676f; // e^{2pi i/3}
  const float CR = 0.86602540378443864676f, SR = 0.5f;                   // e^{2pi i/12}

  // ---- stage A: y staging (wrap pad 2) as [j][n1], rowpair j = rows 2j,2j+1 ----
  float2* yb = R1;                          // [66][134]
  for (int e = tid; e < 66*132; e += 1024) {
    int n1 = e % 132, j = e / 132;
    int col = (n1 + 126) & 127;
    int ra = (2*j + 126) & 127, rb = (2*j + 127) & 127;
    yb[j*134 + n1] = make_float2(xim[ra*NX + col], xim[rb*NX + col]);
  }
  __syncthreads();

  // ---- S1: row DFT, two-for-one, radix-4x3, 3 q/lane ----
  {
    bool act = tid < 726;                   // 66 j * 11 qq
    int j = 0, qq = 0;
    if (act) { j = tid/11; qq = tid - j*11; }
    float s11, c11; sincosf(TWO_PI*(float)qq/11.f, &s11, &c11);
    float s33q, c33q; sincosf(TWO_PI*(float)qq/33.f, &s33q, &c33q);
    float swq, cwq; sincosf(TWO_PI*(float)qq/132.f, &swq, &cwq);
    float c33g[3], s33g[3], cwg[3], swg[3];
    c33g[0] = c33q; s33g[0] = s33q;
    c33g[1] = c33q*CG - s33q*SG;       s33g[1] = s33q*CG + c33q*SG;
    c33g[2] = c33g[1]*CG - s33g[1]*SG; s33g[2] = s33g[1]*CG + c33g[1]*SG;
    cwg[0] = cwq; swg[0] = swq;
    cwg[1] = cwq*CR - swq*SR;          swg[1] = swq*CR + cwq*SR;
    cwg[2] = cwg[1]*CR - swg[1]*SR;    swg[2] = swg[1]*CR + cwg[1]*SR;
    float SSr[3][4], SSi[3][4];
#pragma unroll
    for (int s = 0; s < 3; ++s)
#pragma unroll
      for (int r = 0; r < 4; ++r) { SSr[s][r] = 0.f; SSi[s][r] = 0.f; }
    if (act) {
      const float2* bp = yb + j*134;
      float tr = 1.f, ti = 0.f;
#pragma unroll 1
      for (int t = 0; t < 11; ++t) {
#pragma unroll
        for (int s = 0; s < 3; ++s) {
          float4 d01 = *(const float4*)(bp + 12*t + 4*s);
          float4 d23 = *(const float4*)(bp + 12*t + 4*s + 2);
          CMACF(SSr[s][0], SSi[s][0], d01.x, d01.y, tr, ti);
          CMACF(SSr[s][1], SSi[s][1], d01.z, d01.w, tr, ti);
          CMACF(SSr[s][2], SSi[s][2], d23.x, d23.y, tr, ti);
          CMACF(SSr[s][3], SSi[s][3], d23.z, d23.w, tr, ti);
        }
        { float nt = tr*c11 - ti*s11; ti = tr*s11 + ti*c11; tr = nt; }
      }
    }
    float Zr[3][4], Zi[3][4];               // [g][s]
    if (act) {
#pragma unroll
      for (int g = 0; g < 3; ++g) {
        float cA = c33g[g], sA = s33g[g];
        float cB = cA*cA - sA*sA, sB = 2.f*cA*sA;
        float Sr4[4], Si4[4];
#pragma unroll
        for (int r = 0; r < 4; ++r) {
          float xr = SSr[0][r], xi = SSi[0][r];
          CMACF(xr, xi, SSr[1][r], SSi[1][r], cA, sA);
          CMACF(xr, xi, SSr[2][r], SSi[2][r], cB, sB);
          Sr4[r] = xr; Si4[r] = xi;
        }
        float2 w1 = make_float2(cwg[g], swg[g]);
        float2 w2 = make_float2(w1.x*w1.x - w1.y*w1.y, 2.f*w1.x*w1.y);
        float2 w3 = make_float2(w2.x*w1.x - w2.y*w1.y, w2.x*w1.y + w2.y*w1.x);
#define S1C(sidx, P1, P2, P3) { \
        float zr = Sr4[0], zi = Si4[0]; \
        CMACF(zr, zi, Sr4[1], Si4[1], TR##P1(w1), TI##P1(w1)); \
        CMACF(zr, zi, Sr4[2], Si4[2], TR##P2(w2), TI##P2(w2)); \
        CMACF(zr, zi, Sr4[3], Si4[3], TR##P3(w3), TI##P3(w3)); \
        Zr[g][sidx] = zr; Zi[g][sidx] = zi; }
        S1C(0,0,0,0) S1C(1,1,2,3) S1C(2,2,0,2) S1C(3,3,2,1)
#undef S1C
      }
    }
    __syncthreads();     // all y reads done before Z overwrite
    if (act) {
#pragma unroll
      for (int g = 0; g < 3; ++g) {
        int q = qq + 11*g;
#pragma unroll
        for (int s = 0; s < 4; ++s)
          yb[j*134 + q + 33*s] = make_float2(Zr[g][s], Zi[g][s]);
      }
    }
    __syncthreads();     // Z complete
    if (act) {
      const float2* Zrow = yb + j*134;
      float2* Abase = &R2[(j>>1)*274 + 2*(j&1)];
#pragma unroll
      for (int g = 0; g < 3; ++g) {
        int q = qq + 11*g;
        float2 Za = Zrow[q];
        float2 Zb = Zrow[(132 - q) % 132];
        float2 Zc = Zrow[q + 33];
        float2 Zd = Zrow[99 - q];
        *(float4*)&Abase[q*4] = make_float4(
            0.5f*(Za.x+Zb.x), 0.5f*(Za.y-Zb.y),
            0.5f*(Za.y+Zb.y), 0.5f*(Zb.x-Za.x));
        *(float4*)&Abase[(q+33)*4] = make_float4(
            0.5f*(Zc.x+Zd.x), 0.5f*(Zc.y-Zd.y),
            0.5f*(Zc.y+Zd.y), 0.5f*(Zd.x-Zc.x));
        if (q == 0) {                       // v = 66 (Nyquist)
          float2 Ze = Zrow[66];
          *(float4*)&Abase[66*4] = make_float4(Ze.x, 0.f, Ze.y, 0.f);
        }
      }
    }
  }
  __syncthreads();       // A ready in R2

  // ---- S2+S3: col DFT + H, col IDFT; 3 q/lane, radix-3 m-split ----
  {
    bool act = tid < 737;                   // 67 v * 11 qq
    int v = 0, qq = 0;
    if (act) { v = tid/11; qq = tid - v*11; }
    float s11, c11; sincosf(TWO_PI*(float)qq/11.f, &s11, &c11);
    float s33q, c33q; sincosf(TWO_PI*(float)qq/33.f, &s33q, &c33q);
    float swq, cwq; sincosf(TWO_PI*(float)qq/132.f, &swq, &cwq);
    float c33g[3], s33g[3], cwg[3], swg[3];
    c33g[0] = c33q; s33g[0] = s33q;
    c33g[1] = c33q*CG - s33q*SG;       s33g[1] = s33q*CG + c33q*SG;
    c33g[2] = c33g[1]*CG - s33g[1]*SG; s33g[2] = s33g[1]*CG + c33g[1]*SG;
    cwg[0] = cwq; swg[0] = swq;
    cwg[1] = cwq*CR - swq*SR;          swg[1] = swq*CR + cwq*SR;
    cwg[2] = cwg[1]*CR - swg[1]*SR;    swg[2] = swg[1]*CR + cwg[1]*SR;
    float SSr[3][4], SSi[3][4];   // [s][r] shared sub-sums
    float Sr[4][3], Si[4][3];     // [r][g]
    float2 h[3][4];
#define ZSS() { \
    _Pragma("unroll") for (int s = 0; s < 3; ++s) \
    _Pragma("unroll") for (int r = 0; r < 4; ++r) { SSr[s][r] = 0.f; SSi[s][r] = 0.f; } }
#define S23TLOOP(MAC) { \
    float tr = 1.f, ti = 0.f; \
    const float2* bp = R2 + v*4; \
    _Pragma("unroll 1") \
    for (int t = 0; t < 11; ++t) { \
      _Pragma("unroll") \
      for (int s = 0; s < 3; ++s) { \
        float4 d01 = *(const float4*)(bp + s*274); \
        float4 d23 = *(const float4*)(bp + s*274 + 2); \
        MAC(SSr[s][0], SSi[s][0], d01.x, d01.y, tr, ti); \
        MAC(SSr[s][1], SSi[s][1], d01.z, d01.w, tr, ti); \
        MAC(SSr[s][2], SSi[s][2], d23.x, d23.y, tr, ti); \
        MAC(SSr[s][3], SSi[s][3], d23.z, d23.w, tr, ti); } \
      { float nt = tr*c11 - ti*s11; ti = tr*s11 + ti*c11; tr = nt; } \
      bp += 3*274; \
    } }
#define S23COMB(MAC) { \
    _Pragma("unroll") \
    for (int g = 0; g < 3; ++g) { \
      float cA = c33g[g], sA = s33g[g]; \
      float cB = cA*cA - sA*sA, sB = 2.f*cA*sA; \
      _Pragma("unroll") \
      for (int r = 0; r < 4; ++r) { \
        float xr = SSr[0][r], xi = SSi[0][r]; \
        MAC(xr, xi, SSr[1][r], SSi[1][r], cA, sA); \
        MAC(xr, xi, SSr[2][r], SSi[2][r], cB, sB); \
        Sr[r][g] = xr; Si[r][g] = xi; } } }
    // ---- phase A: forward col-DFT ----
    ZSS();
    if (act) {
      S23TLOOP(CMACF);
      S23COMB(CMACF);
#pragma unroll
      for (int g = 0; g < 3; ++g)
#pragma unroll
        for (int s = 0; s < 4; ++s)
          h[g][s] = Hc[(size_t)v*NP + (qq + 11*g) + 33*s];
    }
    __syncthreads();     // phase-A reads of A done
    if (act) {
#pragma unroll
      for (int g = 0; g < 3; ++g) {
        int q = qq + 11*g;
        float2 w1 = make_float2(cwg[g], swg[g]);
        float2 w2 = make_float2(w1.x*w1.x - w1.y*w1.y, 2.f*w1.x*w1.y);
        float2 w3 = make_float2(w2.x*w1.x - w2.y*w1.y, w2.x*w1.y + w2.y*w1.x);
#define S23A(sidx, P1, P2, P3) { \
        int u = q + 33*(sidx); \
        float xr = Sr[0][g], xi = Si[0][g]; \
        CMACF(xr, xi, Sr[1][g], Si[1][g], TR##P1(w1), TI##P1(w1)); \
        CMACF(xr, xi, Sr[2][g], Si[2][g], TR##P2(w2), TI##P2(w2)); \
        CMACF(xr, xi, Sr[3][g], Si[3][g], TR##P3(w3), TI##P3(w3)); \
        float2 hh = h[g][sidx]; \
        R2[(u>>2)*274 + v*4 + (u&3)] = make_float2(xr*hh.x - xi*hh.y, xr*hh.y + xi*hh.x); }
        S23A(0,0,0,0) S23A(1,1,2,3) S23A(2,2,0,2) S23A(3,3,2,1)
#undef S23A
      }
    }
    __syncthreads();     // T visible
    // ---- phase B: inverse col-DFT ----
    ZSS();
    if (act) {
      S23TLOOP(CMACG);
      S23COMB(CMACG);
#pragma unroll
      for (int g = 0; g < 3; ++g) {
        int q = qq + 11*g;
        float2 w1 = make_float2(cwg[g], swg[g]);
        float2 w2 = make_float2(w1.x*w1.x - w1.y*w1.y, 2.f*w1.x*w1.y);
        float2 w3 = make_float2(w2.x*w1.x - w2.y*w1.y, w2.x*w1.y + w2.y*w1.x);
#define S23B(sidx, P1, P2, P3) { \
        int n0 = q + 33*(sidx); \
        float xr = Sr[0][g], xi = Si[0][g]; \
        CMACG(xr, xi, Sr[1][g], Si[1][g], TR##P1(w1), TI##P1(w1)); \
        CMACG(xr, xi, Sr[2][g], Si[2][g], TR##P2(w2), TI##P2(w2)); \
        CMACG(xr, xi, Sr[3][g], Si[3][g], TR##P3(w3), TI##P3(w3)); \
        R1[v*134 + n0] = make_float2(xr, xi); }
        S23B(0,0,0,0) S23B(1,1,2,3) S23B(2,2,0,2) S23B(3,3,2,1)
#undef S23B
      }
    }
#undef S23TLOOP
#undef S23COMB
#undef ZSS
  }
  __syncthreads();       // U ready in R1; T dead

  // ---- W pre-pass: Hermitian-extended spectrum W[j][v4] -> R2 ----
  {
    float2* Wb = R2;                        // [66][134]
    for (int e = tid; e < 66*132; e += 1024) {
      int v4 = e % 132, j = e / 132;
      int vv = (v4 <= 66) ? v4 : 132 - v4;
      float4 f = *(const float4*)(R1 + vv*134 + 2*j);   // (Ua, Ub)
      float2 w = (v4 <= 66) ? make_float2(f.x - f.w, f.y + f.z)
                            : make_float2(f.x + f.w, f.z - f.y);
      Wb[j*134 + v4] = w;
    }
  }
  __syncthreads();       // W ready; U dead

  // ---- S4: row real-IDFT, radix-4x3, 3 q/lane; rho -> R1 ----
  {
    bool act = tid < 726;                   // 66 j * 11 qq
    int j = 0, qq = 0;
    if (act) { j = tid/11; qq = tid - j*11; }
    float s11, c11; sincosf(TWO_PI*(float)qq/11.f, &s11, &c11);
    float s33q, c33q; sincosf(TWO_PI*(float)qq/33.f, &s33q, &c33q);
    float swq, cwq; sincosf(TWO_PI*(float)qq/132.f, &swq, &cwq);
    float c33g[3], s33g[3], cwg[3], swg[3];
    c33g[0] = c33q; s33g[0] = s33q;
    c33g[1] = c33q*CG - s33q*SG;       s33g[1] = s33q*CG + c33q*SG;
    c33g[2] = c33g[1]*CG - s33g[1]*SG; s33g[2] = s33g[1]*CG + c33g[1]*SG;
    cwg[0] = cwq; swg[0] = swq;
    cwg[1] = cwq*CR - swq*SR;          swg[1] = swq*CR + cwq*SR;
    cwg[2] = cwg[1]*CR - swg[1]*SR;    swg[2] = swg[1]*CR + cwg[1]*SR;
    float SSr[3][4], SSi[3][4];
#pragma unroll
    for (int s = 0; s < 3; ++s)
#pragma unroll
      for (int r = 0; r < 4; ++r) { SSr[s][r] = 0.f; SSi[s][r] = 0.f; }
    if (act) {
      const float2* bp = R2 + j*134;        // W row
      float tr = 1.f, ti = 0.f;
#pragma unroll 1
      for (int t = 0; t < 11; ++t) {
#pragma unroll
        for (int s = 0; s < 3; ++s) {
          float4 d01 = *(const float4*)(bp + 12*t + 4*s);
          float4 d23 = *(const float4*)(bp + 12*t + 4*s + 2);
          CMACG(SSr[s][0], SSi[s][0], d01.x, d01.y, tr, ti);
          CMACG(SSr[s][1], SSi[s][1], d01.z, d01.w, tr, ti);
          CMACG(SSr[s][2], SSi[s][2], d23.x, d23.y, tr, ti);
          CMACG(SSr[s][3], SSi[s][3], d23.z, d23.w, tr, ti);
        }
        { float nt = tr*c11 - ti*s11; ti = tr*s11 + ti*c11; tr = nt; }
      }
    }
    __syncthreads();     // all W reads done; R1 free for rho
    if (act) {
      float* rho2 = (float*)R1;             // [132][136]
      const float scale = 1.0f/(float)NPP;
#pragma unroll
      for (int g = 0; g < 3; ++g) {
        int q = qq + 11*g;
        float cA = c33g[g], sA = s33g[g];
        float cB = cA*cA - sA*sA, sB = 2.f*cA*sA;
        float Sr4[4], Si4[4];
#pragma unroll
        for (int r = 0; r < 4; ++r) {
          float xr = SSr[0][r], xi = SSi[0][r];
          CMACG(xr, xi, SSr[1][r], SSi[1][r], cA, sA);
          CMACG(xr, xi, SSr[2][r], SSi[2][r], cB, sB);
          Sr4[r] = xr; Si4[r] = xi;
        }
        float2 w1 = make_float2(cwg[g], swg[g]);
        float2 w2 = make_float2(w1.x*w1.x - w1.y*w1.y, 2.f*w1.x*w1.y);
        float2 w3 = make_float2(w2.x*w1.x - w2.y*w1.y, w2.x*w1.y + w2.y*w1.x);
#define S4C(sidx, P1, P2, P3) { \
        int n1 = q + 33*(sidx); \
        float zr = Sr4[0], zi = Si4[0]; \
        CMACG(zr, zi, Sr4[1], Si4[1], TR##P1(w1), TI##P1(w1)); \
        CMACG(zr, zi, Sr4[2], Si4[2], TR##P2(w2), TI##P2(w2)); \
        CMACG(zr, zi, Sr4[3], Si4[3], TR##P3(w3), TI##P3(w3)); \
        rho2[(2*j)*136 + n1] = zr*scale; \
        rho2[(2*j+1)*136 + n1] = zi*scale; }
        S4C(0,0,0,0) S4C(1,1,2,3) S4C(2,2,0,2) S4C(3,3,2,1)
#undef S4C
      }
    }
  }
  __syncthreads();       // rho ready

  // ---- epilogue: out = gelu(x_up + subpixel taps of K over rho) ----
  {
    const float* rho2 = (const float*)R1;
    const float* w = wgt + c*9;
    float k0=w[0], k1=w[1], k2=w[2], k3=w[3], k4=w[4], k5=w[5], k6=w[6], k7=w[7], k8=w[8];
    float* outim = out + (size_t)img*NO*NO;
    for (int e = tid; e < NO*NO; e += 1024) {
      int o1 = e & 255, o0 = e >> 8;
      int n0 = (o0 + 4) >> 1, n1 = (o1 + 4) >> 1;
      int p0 = o0 & 1, p1 = o1 & 1;
      int base = n0*136 + n1;
      float r00 = rho2[base],     r01 = rho2[base+1];
      float r10 = rho2[base+136], r11 = rho2[base+137];
      float wa = p0 ? (p1 ? k0 : k1) : (p1 ? k3 : k4);
      float wb = p1 ? (p0 ? k2 : k5) : 0.f;
      float wc = p0 ? (p1 ? k6 : k7) : 0.f;
      float wd = (p0 & p1) ? k8 : 0.f;
      float S = wa*r00 + wb*r01 + wc*r10 + wd*r11;
      float xv = xim[(n0-2)*NX + (n1-2)];
      float z = xv + S;
      outim[e] = 0.5f*z*(1.0f + erff(z*0.70710678118654752f));
    }
  }
}

extern "C" void kernel_launch(void* const* d_in, const int* in_sizes, int n_in,
                              void* d_out, int out_size, void* d_ws, size_t ws_size,
                              hipStream_t stream) {
  const float* x    = (const float*)d_in[0];
  const float* wgt  = (const float*)d_in[1];
  const float* bias = (const float*)d_in[2];
  float* ws = (float*)d_ws;
  float2* H = (float2*)(ws + OFF_H);
  float* out = (float*)d_out;

  k_compute_H<<<dim3((NV*NP + 255)/256, NCH), 256, 0, stream>>>(wgt, bias, H);
  k_fused<<<dim3(NIMG), 1024, 0, stream>>>(x, wgt, H, out);   // 1 image/block, 1 block/CU
}

// Round 12
// 134.457 us; speedup vs baseline: 1.6930x; 1.0709x over previous
//
#include <hip/hip_runtime.h>
#include <math.h>

#define NP   132
#define NV   67            // Hermitian half-spectrum (0..66), 66 = Nyquist
#define NPP  (NP*NP)       // 17424
#define NCH  64
#define NIMG 256
#define NX   128
#define NO   256
#define TWO_PI 6.2831853071795864769f

// ws layout (floats): H : [NCH][NV][132][2] transfer fn, [c][v][u]
static const size_t OFF_H = 0;

// i-power sign/swap: multiplier i^p (g-form) or (-i)^p (f-form)
#define TR0(t) (t.x)
#define TI0(t) (t.y)
#define TR1(t) (-(t.y))
#define TI1(t) (t.x)
#define TR2(t) (-(t.x))
#define TI2(t) (-(t.y))
#define TR3(t) (t.y)
#define TI3(t) (-(t.x))
#define CMACF(xr, xi, dr, di, TRv, TIv) { xr += (dr)*(TRv) + (di)*(TIv); xi += (di)*(TRv) - (dr)*(TIv); }
#define CMACG(xr, xi, dr, di, TRv, TIv) { xr += (dr)*(TRv) - (di)*(TIv); xi += (di)*(TRv) + (dr)*(TIv); }

__global__ __launch_bounds__(256) void k_compute_H(
    const float* __restrict__ wgt, const float* __restrict__ bias,
    float2* __restrict__ H) {
  int idx = blockIdx.x * 256 + threadIdx.x;   // over NV*NP
  int c = blockIdx.y;
  if (idx >= NV*NP) return;
  int u = idx % NP, v = idx / NP;
  float k[3][3];
#pragma unroll
  for (int i = 0; i < 3; i++)
#pragma unroll
    for (int j = 0; j < 3; j++) k[i][j] = wgt[c*9 + i*3 + j];
  // invW closed form via autocorrelation symmetry s(p)=s(-p):
  // invW = s00 + 2[s10 cu + s01 cv + s11 cuv + s1m1 cos(u-v)]
  float s00 = 0.f;
#pragma unroll
  for (int i = 0; i < 3; i++)
#pragma unroll
    for (int j = 0; j < 3; j++) s00 += k[i][j]*k[i][j];
  float s10 = k[2][0]*k[0][0] + k[2][1]*k[0][1] + k[2][2]*k[0][2];
  float s01 = k[0][2]*k[0][0] + k[1][2]*k[1][0] + k[2][2]*k[2][0];
  float s11p = k[2][2]*k[0][0];
  float s1m1 = k[2][0]*k[0][2];
  float B00 = k[0][0]+k[0][1]+k[1][0]+k[1][1];
  float B10 = k[2][0]+k[2][1];
  float B01 = k[0][2]+k[1][2];
  float B11 = k[2][2];
  float su, cu, sv, cv, suv, cuv;
  sincosf(TWO_PI*(float)u/(float)NP, &su, &cu);
  sincosf(TWO_PI*(float)v/(float)NP, &sv, &cv);
  sincosf(TWO_PI*(float)(u+v)/(float)NP, &suv, &cuv);
  float cumv = cu*cv + su*sv;                 // cos(2pi(u-v)/132)
  float invW = s00 + 2.f*(s10*cu + s01*cv + s11p*cuv + s1m1*cumv);
  float Bre = B00 + B10*cu + B01*cv + B11*cuv;
  float Bim = -(B10*su + B01*sv + B11*suv);
  float alpha = 1.f/(1.f + expf(9.f - bias[c])) + 1e-5f;
  float d = invW + alpha;
  H[((size_t)c*NV + v)*NP + u] = make_float2((1.f - Bre)/d, (-Bim)/d);
}

// Fully fused per image (one block, 1024 thr), all intermediates in LDS.
// All DFT stages use radix-4 x radix-3 with lane map tid = row*11 + qq:
// qq = tid%11 is IDENTICAL across stages -> all twiddles (w11, w33 per g,
// w132 per g, radix-4 combine w2/w3) computed ONCE per lane at entry.
// R1 (71.9KB): y/Z [j=rowpair][n1] stride 134 -> U [v][134] -> rho [132][136] floats
// R2 (72.3KB): A/T [m][v*4+r] stride 274 -> W [j][v4] stride 134
__global__ __launch_bounds__(1024, 4) void k_fused(
    const float* __restrict__ x, const float* __restrict__ wgt,
    const float2* __restrict__ H, float* __restrict__ out) {
  __shared__ __align__(16) float2 R1[67*134 + 4];
  __shared__ __align__(16) float2 R2[33*274];
  int tid = threadIdx.x;
  int img = blockIdx.x;
  int c = img & 63;
  const float* xim = x + (size_t)img*NX*NX;
  const float2* Hc = H + (size_t)c*NV*NP;
  const float CG = -0.5f,                  SG = 0.86602540378443864676f; // e^{2pi i/3}
  const float CR = 0.86602540378443864676f, SR = 0.5f;                   // e^{2pi i/12}

  // ---- universal per-lane twiddles (qq = tid%11, shared by S1/S23/S4) ----
  int qq = tid % 11;
  float s11u, c11u; sincosf(TWO_PI*(float)qq/11.f, &s11u, &c11u);
  float s33q, c33q; sincosf(TWO_PI*(float)qq/33.f, &s33q, &c33q);
  float swq, cwq;   sincosf(TWO_PI*(float)qq/132.f, &swq, &cwq);
  float c33g[3], s33g[3];
  c33g[0] = c33q;                    s33g[0] = s33q;
  c33g[1] = c33q*CG - s33q*SG;       s33g[1] = s33q*CG + c33q*SG;
  c33g[2] = c33g[1]*CG - s33g[1]*SG; s33g[2] = s33g[1]*CG + c33g[1]*SG;
  float w1r[3], w1i[3], w2r[3], w2i[3], w3r[3], w3i[3];
  w1r[0] = cwq;                      w1i[0] = swq;
  w1r[1] = cwq*CR - swq*SR;          w1i[1] = swq*CR + cwq*SR;
  w1r[2] = w1r[1]*CR - w1i[1]*SR;    w1i[2] = w1i[1]*CR + w1r[1]*SR;
#pragma unroll
  for (int g = 0; g < 3; ++g) {
    w2r[g] = w1r[g]*w1r[g] - w1i[g]*w1i[g];
    w2i[g] = 2.f*w1r[g]*w1i[g];
    w3r[g] = w2r[g]*w1r[g] - w2i[g]*w1i[g];
    w3i[g] = w2r[g]*w1i[g] + w2i[g]*w1r[g];
  }

  // ---- stage A: y staging (wrap pad 2) as [j][n1], rowpair j = rows 2j,2j+1 ----
  float2* yb = R1;                          // [66][134]
  for (int e = tid; e < 66*132; e += 1024) {
    int n1 = e % 132, j = e / 132;
    int col = (n1 + 126) & 127;
    int ra = (2*j + 126) & 127, rb = (2*j + 127) & 127;
    yb[j*134 + n1] = make_float2(xim[ra*NX + col], xim[rb*NX + col]);
  }
  __syncthreads();

  // ---- S1: row DFT, two-for-one, radix-4x3, 3 q/lane ----
  {
    bool act = tid < 726;                   // 66 j * 11 qq
    int j = act ? tid/11 : 0;
    float SSr[3][4], SSi[3][4];
#pragma unroll
    for (int s = 0; s < 3; ++s)
#pragma unroll
      for (int r = 0; r < 4; ++r) { SSr[s][r] = 0.f; SSi[s][r] = 0.f; }
    if (act) {
      const float2* bp = yb + j*134;
      float tr = 1.f, ti = 0.f;
#pragma unroll 1
      for (int t = 0; t < 11; ++t) {
#pragma unroll
        for (int s = 0; s < 3; ++s) {
          float4 d01 = *(const float4*)(bp + 12*t + 4*s);
          float4 d23 = *(const float4*)(bp + 12*t + 4*s + 2);
          CMACF(SSr[s][0], SSi[s][0], d01.x, d01.y, tr, ti);
          CMACF(SSr[s][1], SSi[s][1], d01.z, d01.w, tr, ti);
          CMACF(SSr[s][2], SSi[s][2], d23.x, d23.y, tr, ti);
          CMACF(SSr[s][3], SSi[s][3], d23.z, d23.w, tr, ti);
        }
        { float nt = tr*c11u - ti*s11u; ti = tr*s11u + ti*c11u; tr = nt; }
      }
    }
    float Zr[3][4], Zi[3][4];               // [g][s]
    if (act) {
#pragma unroll
      for (int g = 0; g < 3; ++g) {
        float cA = c33g[g], sA = s33g[g];
        float cB = cA*cA - sA*sA, sB = 2.f*cA*sA;
        float Sr4[4], Si4[4];
#pragma unroll
        for (int r = 0; r < 4; ++r) {
          float xr = SSr[0][r], xi = SSi[0][r];
          CMACF(xr, xi, SSr[1][r], SSi[1][r], cA, sA);
          CMACF(xr, xi, SSr[2][r], SSi[2][r], cB, sB);
          Sr4[r] = xr; Si4[r] = xi;
        }
        float2 w1 = make_float2(w1r[g], w1i[g]);
        float2 w2 = make_float2(w2r[g], w2i[g]);
        float2 w3 = make_float2(w3r[g], w3i[g]);
#define S1C(sidx, P1, P2, P3) { \
        float zr = Sr4[0], zi = Si4[0]; \
        CMACF(zr, zi, Sr4[1], Si4[1], TR##P1(w1), TI##P1(w1)); \
        CMACF(zr, zi, Sr4[2], Si4[2], TR##P2(w2), TI##P2(w2)); \
        CMACF(zr, zi, Sr4[3], Si4[3], TR##P3(w3), TI##P3(w3)); \
        Zr[g][sidx] = zr; Zi[g][sidx] = zi; }
        S1C(0,0,0,0) S1C(1,1,2,3) S1C(2,2,0,2) S1C(3,3,2,1)
#undef S1C
      }
    }
    __syncthreads();     // all y reads done before Z overwrite
    if (act) {
#pragma unroll
      for (int g = 0; g < 3; ++g) {
        int q = qq + 11*g;
#pragma unroll
        for (int s = 0; s < 4; ++s)
          yb[j*134 + q + 33*s] = make_float2(Zr[g][s], Zi[g][s]);
      }
    }
    __syncthreads();     // Z complete
    if (act) {
      const float2* Zrow = yb + j*134;
      float2* Abase = &R2[(j>>1)*274 + 2*(j&1)];
#pragma unroll
      for (int g = 0; g < 3; ++g) {
        int q = qq + 11*g;
        float2 Za = Zrow[q];
        float2 Zb = Zrow[(132 - q) % 132];
        float2 Zc = Zrow[q + 33];
        float2 Zd = Zrow[99 - q];
        *(float4*)&Abase[q*4] = make_float4(
            0.5f*(Za.x+Zb.x), 0.5f*(Za.y-Zb.y),
            0.5f*(Za.y+Zb.y), 0.5f*(Zb.x-Za.x));
        *(float4*)&Abase[(q+33)*4] = make_float4(
            0.5f*(Zc.x+Zd.x), 0.5f*(Zc.y-Zd.y),
            0.5f*(Zc.y+Zd.y), 0.5f*(Zd.x-Zc.x));
        if (q == 0) {                       // v = 66 (Nyquist)
          float2 Ze = Zrow[66];
          *(float4*)&Abase[66*4] = make_float4(Ze.x, 0.f, Ze.y, 0.f);
        }
      }
    }
  }
  __syncthreads();       // A ready in R2

  // ---- S2+S3: col DFT + H, col IDFT; 3 q/lane, radix-3 m-split ----
  {
    bool act = tid < 737;                   // 67 v * 11 qq
    int v = act ? tid/11 : 0;
    float SSr[3][4], SSi[3][4];   // [s][r] shared sub-sums
    float Sr[4][3], Si[4][3];     // [r][g]
    float2 h[3][4];
#define ZSS() { \
    _Pragma("unroll") for (int s = 0; s < 3; ++s) \
    _Pragma("unroll") for (int r = 0; r < 4; ++r) { SSr[s][r] = 0.f; SSi[s][r] = 0.f; } }
#define S23TLOOP(MAC) { \
    float tr = 1.f, ti = 0.f; \
    const float2* bp = R2 + v*4; \
    _Pragma("unroll 1") \
    for (int t = 0; t < 11; ++t) { \
      _Pragma("unroll") \
      for (int s = 0; s < 3; ++s) { \
        float4 d01 = *(const float4*)(bp + s*274); \
        float4 d23 = *(const float4*)(bp + s*274 + 2); \
        MAC(SSr[s][0], SSi[s][0], d01.x, d01.y, tr, ti); \
        MAC(SSr[s][1], SSi[s][1], d01.z, d01.w, tr, ti); \
        MAC(SSr[s][2], SSi[s][2], d23.x, d23.y, tr, ti); \
        MAC(SSr[s][3], SSi[s][3], d23.z, d23.w, tr, ti); } \
      { float nt = tr*c11u - ti*s11u; ti = tr*s11u + ti*c11u; tr = nt; } \
      bp += 3*274; \
    } }
#define S23COMB(MAC) { \
    _Pragma("unroll") \
    for (int g = 0; g < 3; ++g) { \
      float cA = c33g[g], sA = s33g[g]; \
      float cB = cA*cA - sA*sA, sB = 2.f*cA*sA; \
      _Pragma("unroll") \
      for (int r = 0; r < 4; ++r) { \
        float xr = SSr[0][r], xi = SSi[0][r]; \
        MAC(xr, xi, SSr[1][r], SSi[1][r], cA, sA); \
        MAC(xr, xi, SSr[2][r], SSi[2][r], cB, sB); \
        Sr[r][g] = xr; Si[r][g] = xi; } } }
    // ---- phase A: forward col-DFT ----
    ZSS();
    if (act) {
      S23TLOOP(CMACF);
      S23COMB(CMACF);
#pragma unroll
      for (int g = 0; g < 3; ++g)
#pragma unroll
        for (int s = 0; s < 4; ++s)
          h[g][s] = Hc[(size_t)v*NP + (qq + 11*g) + 33*s];
    }
    __syncthreads();     // phase-A reads of A done
    if (act) {
#pragma unroll
      for (int g = 0; g < 3; ++g) {
        int q = qq + 11*g;
        float2 w1 = make_float2(w1r[g], w1i[g]);
        float2 w2 = make_float2(w2r[g], w2i[g]);
        float2 w3 = make_float2(w3r[g], w3i[g]);
#define S23A(sidx, P1, P2, P3) { \
        int u = q + 33*(sidx); \
        float xr = Sr[0][g], xi = Si[0][g]; \
        CMACF(xr, xi, Sr[1][g], Si[1][g], TR##P1(w1), TI##P1(w1)); \
        CMACF(xr, xi, Sr[2][g], Si[2][g], TR##P2(w2), TI##P2(w2)); \
        CMACF(xr, xi, Sr[3][g], Si[3][g], TR##P3(w3), TI##P3(w3)); \
        float2 hh = h[g][sidx]; \
        R2[(u>>2)*274 + v*4 + (u&3)] = make_float2(xr*hh.x - xi*hh.y, xr*hh.y + xi*hh.x); }
        S23A(0,0,0,0) S23A(1,1,2,3) S23A(2,2,0,2) S23A(3,3,2,1)
#undef S23A
      }
    }
    __syncthreads();     // T visible
    // ---- phase B: inverse col-DFT ----
    ZSS();
    if (act) {
      S23TLOOP(CMACG);
      S23COMB(CMACG);
#pragma unroll
      for (int g = 0; g < 3; ++g) {
        int q = qq + 11*g;
        float2 w1 = make_float2(w1r[g], w1i[g]);
        float2 w2 = make_float2(w2r[g], w2i[g]);
        float2 w3 = make_float2(w3r[g], w3i[g]);
#define S23B(sidx, P1, P2, P3) { \
        int n0 = q + 33*(sidx); \
        float xr = Sr[0][g], xi = Si[0][g]; \
        CMACG(xr, xi, Sr[1][g], Si[1][g], TR##P1(w1), TI##P1(w1)); \
        CMACG(xr, xi, Sr[2][g], Si[2][g], TR##P2(w2), TI##P2(w2)); \
        CMACG(xr, xi, Sr[3][g], Si[3][g], TR##P3(w3), TI##P3(w3)); \
        R1[v*134 + n0] = make_float2(xr, xi); }
        S23B(0,0,0,0) S23B(1,1,2,3) S23B(2,2,0,2) S23B(3,3,2,1)
#undef S23B
      }
    }
#undef S23TLOOP
#undef S23COMB
#undef ZSS
  }
  __syncthreads();       // U ready in R1; T dead

  // ---- W pre-pass: Hermitian-extended spectrum W[j][v4] -> R2 ----
  {
    float2* Wb = R2;                        // [66][134]
    for (int e = tid; e < 66*132; e += 1024) {
      int v4 = e % 132, j = e / 132;
      int vv = (v4 <= 66) ? v4 : 132 - v4;
      float4 f = *(const float4*)(R1 + vv*134 + 2*j);   // (Ua, Ub)
      float2 w = (v4 <= 66) ? make_float2(f.x - f.w, f.y + f.z)
                            : make_float2(f.x + f.w, f.z - f.y);
      Wb[j*134 + v4] = w;
    }
  }
  __syncthreads();       // W ready; U dead

  // ---- S4: row real-IDFT, radix-4x3, 3 q/lane; rho -> R1 ----
  {
    bool act = tid < 726;                   // 66 j * 11 qq
    int j = act ? tid/11 : 0;
    float SSr[3][4], SSi[3][4];
#pragma unroll
    for (int s = 0; s < 3; ++s)
#pragma unroll
      for (int r = 0; r < 4; ++r) { SSr[s][r] = 0.f; SSi[s][r] = 0.f; }
    if (act) {
      const float2* bp = R2 + j*134;        // W row
      float tr = 1.f, ti = 0.f;
#pragma unroll 1
      for (int t = 0; t < 11; ++t) {
#pragma unroll
        for (int s = 0; s < 3; ++s) {
          float4 d01 = *(const float4*)(bp + 12*t + 4*s);
          float4 d23 = *(const float4*)(bp + 12*t + 4*s + 2);
          CMACG(SSr[s][0], SSi[s][0], d01.x, d01.y, tr, ti);
          CMACG(SSr[s][1], SSi[s][1], d01.z, d01.w, tr, ti);
          CMACG(SSr[s][2], SSi[s][2], d23.x, d23.y, tr, ti);
          CMACG(SSr[s][3], SSi[s][3], d23.z, d23.w, tr, ti);
        }
        { float nt = tr*c11u - ti*s11u; ti = tr*s11u + ti*c11u; tr = nt; }
      }
    }
    __syncthreads();     // all W reads done; R1 free for rho
    if (act) {
      float* rho2 = (float*)R1;             // [132][136]
      const float scale = 1.0f/(float)NPP;
#pragma unroll
      for (int g = 0; g < 3; ++g) {
        int q = qq + 11*g;
        float cA = c33g[g], sA = s33g[g];
        float cB = cA*cA - sA*sA, sB = 2.f*cA*sA;
        float Sr4[4], Si4[4];
#pragma unroll
        for (int r = 0; r < 4; ++r) {
          float xr = SSr[0][r], xi = SSi[0][r];
          CMACG(xr, xi, SSr[1][r], SSi[1][r], cA, sA);
          CMACG(xr, xi, SSr[2][r], SSi[2][r], cB, sB);
          Sr4[r] = xr; Si4[r] = xi;
        }
        float2 w1 = make_float2(w1r[g], w1i[g]);
        float2 w2 = make_float2(w2r[g], w2i[g]);
        float2 w3 = make_float2(w3r[g], w3i[g]);
#define S4C(sidx, P1, P2, P3) { \
        int n1 = q + 33*(sidx); \
        float zr = Sr4[0], zi = Si4[0]; \
        CMACG(zr, zi, Sr4[1], Si4[1], TR##P1(w1), TI##P1(w1)); \
        CMACG(zr, zi, Sr4[2], Si4[2], TR##P2(w2), TI##P2(w2)); \
        CMACG(zr, zi, Sr4[3], Si4[3], TR##P3(w3), TI##P3(w3)); \
        rho2[(2*j)*136 + n1] = zr*scale; \
        rho2[(2*j+1)*136 + n1] = zi*scale; }
        S4C(0,0,0,0) S4C(1,1,2,3) S4C(2,2,0,2) S4C(3,3,2,1)
#undef S4C
      }
    }
  }
  __syncthreads();       // rho ready

  // ---- epilogue: 1 thread = one 2x2 output quad (shared rho/x reads) ----
  {
    const float* rho2 = (const float*)R1;
    const float* w = wgt + c*9;
    float k0=w[0], k1=w[1], k2=w[2], k3=w[3], k4=w[4], k5=w[5], k6=w[6], k7=w[7], k8=w[8];
    float* outim = out + (size_t)img*NO*NO;
#define GELU(z) (0.5f*(z)*(1.0f + erff((z)*0.70710678118654752f)))
    for (int e = tid; e < 128*128; e += 1024) {
      int b = e & 127, a = e >> 7;
      int base = (a+2)*136 + (b+2);
      float r00 = rho2[base],     r01 = rho2[base+1];
      float r10 = rho2[base+136], r11 = rho2[base+137];
      float xv = xim[a*NX + b];
      float z00 = xv + k4*r00;
      float z01 = xv + k3*r00 + k5*r01;
      float z10 = xv + k1*r00 + k7*r10;
      float z11 = xv + k0*r00 + k2*r01 + k6*r10 + k8*r11;
      float2 row0 = make_float2(GELU(z00), GELU(z01));
      float2 row1 = make_float2(GELU(z10), GELU(z11));
      *(float2*)&outim[(2*a)*NO + 2*b] = row0;
      *(float2*)&outim[(2*a+1)*NO + 2*b] = row1;
    }
#undef GELU
  }
}

extern "C" void kernel_launch(void* const* d_in, const int* in_sizes, int n_in,
                              void* d_out, int out_size, void* d_ws, size_t ws_size,
                              hipStream_t stream) {
  const float* x    = (const float*)d_in[0];
  const float* wgt  = (const float*)d_in[1];
  const float* bias = (const float*)d_in[2];
  float* ws = (float*)d_ws;
  float2* H = (float2*)(ws + OFF_H);
  float* out = (float*)d_out;

  k_compute_H<<<dim3((NV*NP + 255)/256, NCH), 256, 0, stream>>>(wgt, bias, H);
  k_fused<<<dim3(NIMG), 1024, 0, stream>>>(x, wgt, H, out);   // 1 image/block, 1 block/CU
}